// Round 1
// baseline (29655.112 us; speedup 1.0000x reference)
//
#include <hip/hip_runtime.h>
#include <hip/hip_bf16.h>
#include <cstdint>

#define CDIV(a,b) (((a)+(b)-1)/(b))

// ================= encoder conv0: 1->256, 28->14, stride2 pad1, relu ============
__global__ __launch_bounds__(256) void conv_e0_kernel(
    const float* __restrict__ x, const float* __restrict__ W,
    const float* __restrict__ b, float* __restrict__ out)
{
  __shared__ float s_img[784];
  const int n = blockIdx.x;
  const int co = threadIdx.x;
  for (int i = threadIdx.x; i < 784; i += 256) s_img[i] = x[(size_t)n*784 + i];
  float w[9];
#pragma unroll
  for (int t = 0; t < 9; ++t) w[t] = W[co*9 + t];
  const float bb = b[co];
  __syncthreads();
  float* orow = out + ((size_t)n*256 + co)*196;
  for (int p = 0; p < 196; ++p) {
    int y = p / 14, xo = p % 14;
    float a = bb;
#pragma unroll
    for (int t = 0; t < 9; ++t) {
      int yi = 2*y + t/3 - 1, xi = 2*xo + t%3 - 1;
      if (yi >= 0 && yi < 28 && xi >= 0 && xi < 28) a = fmaf(w[t], s_img[yi*28 + xi], a);
    }
    orow[p] = fmaxf(a, 0.f);
  }
}

// ================= generic 256->256 3x3 conv, register-tiled ====================
// threads 16(tx) x 16(ty); thread computes TO cout x TP positions.
template<int TO, int TP, int STRIDE, int PAD, int HIN, int WIN, int HOUT, int WOUT, int ACT>
__global__ __launch_bounds__(256) void conv3x3_kernel(
    const float* __restrict__ in, const float* __restrict__ W,
    const float* __restrict__ bias, float* __restrict__ out)
{
  constexpr int TX = 16;
  constexpr int BLK_CO = TX * TO;
  constexpr int BLK_P  = 16 * TP;
  constexpr int PTR_ = ((BLK_P / WOUT) < HOUT) ? (BLK_P / WOUT) : HOUT; // rows per tile
  constexpr int NPOS = PTR_ * WOUT;
  constexpr int RIN = (PTR_ - 1) * STRIDE + 3;
  constexpr int WS  = (WOUT - 1) * STRIDE + 3;
  constexpr int CIC = 8;
  constexpr int CIN = 256;

  __shared__ float s_in[CIC * RIN * WS];
  __shared__ float s_w[TO * 9 * CIC * TX];   // layout ((i*72 + ci*9 + t)*16 + tx) -> conflict-free

  const int n   = blockIdx.x;
  const int cob = blockIdx.y * BLK_CO;
  const int oy0 = blockIdx.z * PTR_;

  const int tid = threadIdx.x;
  const int tx = tid & 15;
  const int ty = tid >> 4;

  int  boff[TP]; int px_[TP]; int pyg[TP]; bool val[TP];
#pragma unroll
  for (int j = 0; j < TP; ++j) {
    int p = ty * TP + j;
    int yl = p / WOUT, xx = p % WOUT;
    val[j] = (p < NPOS) && (oy0 + yl < HOUT);
    px_[j] = xx;
    pyg[j] = oy0 + yl;
    boff[j] = (p < NPOS) ? (yl * STRIDE * WS + xx * STRIDE) : 0;
  }

  float acc[TO][TP];
#pragma unroll
  for (int i = 0; i < TO; ++i)
#pragma unroll
    for (int j = 0; j < TP; ++j) acc[i][j] = 0.f;

  for (int ci0 = 0; ci0 < CIN; ci0 += CIC) {
    for (int idx = tid; idx < CIC*RIN*WS; idx += 256) {
      int ci  = idx / (RIN*WS);
      int rem = idx % (RIN*WS);
      int r = rem / WS, cc = rem % WS;
      int yi = oy0*STRIDE + r - PAD;
      int xi = cc - PAD;
      float v = 0.f;
      if (yi >= 0 && yi < HIN && xi >= 0 && xi < WIN)
        v = in[((size_t)n*CIN + ci0 + ci)*(HIN*WIN) + yi*WIN + xi];
      s_in[idx] = v;
    }
    for (int idx = tid; idx < BLK_CO*CIC*9; idx += 256) {
      int col = idx / 72;          // local cout
      int rem = idx % 72;          // ci*9 + t
      float v = W[((size_t)(cob + col)*CIN + ci0)*9 + rem];
      int txw = col / TO, iw = col % TO;
      s_w[(iw*72 + rem)*TX + txw] = v;
    }
    __syncthreads();
#pragma unroll
    for (int ci = 0; ci < CIC; ++ci) {
#pragma unroll
      for (int t = 0; t < 9; ++t) {
        const int kyws = (t/3)*WS + (t%3);
        float wv[TO];
#pragma unroll
        for (int i = 0; i < TO; ++i) wv[i] = s_w[(i*72 + ci*9 + t)*TX + tx];
        float iv[TP];
#pragma unroll
        for (int j = 0; j < TP; ++j) iv[j] = s_in[ci*(RIN*WS) + boff[j] + kyws];
#pragma unroll
        for (int i = 0; i < TO; ++i)
#pragma unroll
          for (int j = 0; j < TP; ++j) acc[i][j] = fmaf(wv[i], iv[j], acc[i][j]);
      }
    }
    __syncthreads();
  }

#pragma unroll
  for (int i = 0; i < TO; ++i) {
    const int co = cob + tx*TO + i;
    const float bb = bias[co];
#pragma unroll
    for (int j = 0; j < TP; ++j) {
      if (!val[j]) continue;
      float v = acc[i][j] + bb;
      if (ACT == 1) v = fmaxf(v, 0.f);
      out[((size_t)n*256 + co)*(HOUT*WOUT) + pyg[j]*WOUT + px_[j]] = v;
    }
  }
}

// ================= output conv: 256->1, 3x3 pad1, sigmoid =======================
__global__ __launch_bounds__(256) void conv_out_kernel(
    const float* __restrict__ in, const float* __restrict__ W,
    const float* __restrict__ b, float* __restrict__ out)
{
  const int n = blockIdx.x;
  const int tid = threadIdx.x;
  __shared__ float s_in[8][30][30];
  __shared__ float s_w[8][9];
  float acc[4] = {0.f, 0.f, 0.f, 0.f};
  for (int ci0 = 0; ci0 < 256; ci0 += 8) {
    for (int idx = tid; idx < 8*900; idx += 256) {
      int ci = idx / 900; int rem = idx % 900; int r = rem / 30, cc = rem % 30;
      int yi = r - 1, xi = cc - 1;
      float v = 0.f;
      if (yi >= 0 && yi < 28 && xi >= 0 && xi < 28)
        v = in[((size_t)n*256 + ci0 + ci)*784 + yi*28 + xi];
      s_in[ci][r][cc] = v;
    }
    if (tid < 72) s_w[tid/9][tid%9] = W[(ci0 + tid/9)*9 + tid%9];
    __syncthreads();
#pragma unroll
    for (int q = 0; q < 4; ++q) {
      int p = tid + q*256;
      if (p < 784) {
        int y = p / 28, xx = p % 28;
        float a = 0.f;
#pragma unroll
        for (int ci = 0; ci < 8; ++ci)
#pragma unroll
          for (int t = 0; t < 9; ++t)
            a = fmaf(s_w[ci][t], s_in[ci][y + t/3][xx + t%3], a);
        acc[q] += a;
      }
    }
    __syncthreads();
  }
  const float bb = b[0];
  for (int q = 0; q < 4; ++q) {
    int p = tid + q*256;
    if (p < 784) out[(size_t)n*784 + p] = 1.f/(1.f + expf(-(acc[q] + bb)));
  }
}

// ================= bilinear x2 upsample, align_corners=True =====================
template<int H, int W>
__global__ __launch_bounds__(256) void upsample2_kernel(
    const float* __restrict__ in, float* __restrict__ out, int total)
{
  const int idx = blockIdx.x*256 + threadIdx.x;
  if (idx >= total) return;
  constexpr int Ho = 2*H, Wo = 2*W;
  const int xo = idx % Wo;
  const int yo = (idx / Wo) % Ho;
  const int nc = idx / (Wo*Ho);
  const float ys = (float)(yo*(H-1)) / (float)(Ho-1);
  const float xs = (float)(xo*(W-1)) / (float)(Wo-1);
  int y0 = (int)ys; int y1 = (y0+1 < H) ? y0+1 : H-1;
  int x0 = (int)xs; int x1 = (x0+1 < W) ? x0+1 : W-1;
  const float wy = ys - (float)y0, wx = xs - (float)x0;
  const float* base = in + (size_t)nc*(H*W);
  const float v00 = base[y0*W+x0], v01 = base[y0*W+x1];
  const float v10 = base[y1*W+x0], v11 = base[y1*W+x1];
  const float r0 = v00*(1.f-wy) + v10*wy;
  const float r1 = v01*(1.f-wy) + v11*wy;
  out[idx] = r0*(1.f-wx) + r1*wx;
}

// ================= VQ pieces ====================================================
__global__ __launch_bounds__(256) void enorm_kernel(
    const float* __restrict__ E, float* __restrict__ norms)
{
  const int k = blockIdx.x;
  const float4* row = (const float4*)(E + (size_t)k*4096);
  float s = 0.f;
  for (int i = threadIdx.x; i < 1024; i += 256) {
    float4 v = row[i];
    s += v.x*v.x + v.y*v.y + v.z*v.z + v.w*v.w;
  }
  __shared__ float red[256];
  red[threadIdx.x] = s; __syncthreads();
  for (int off = 128; off > 0; off >>= 1) {
    if (threadIdx.x < off) red[threadIdx.x] += red[threadIdx.x + off];
    __syncthreads();
  }
  if (threadIdx.x == 0) norms[k] = red[0];
}

// stable counting-sort permutation by class; also inits keys
__global__ __launch_bounds__(512) void perm_kernel(
    const int* __restrict__ c, int* __restrict__ perm, int* __restrict__ off,
    unsigned long long* __restrict__ keys)
{
  __shared__ int sc[512];
  __shared__ int cnt[8];
  __shared__ int base[9];
  const int i = threadIdx.x;
  sc[i] = c[i];
  if (i < 8) cnt[i] = 0;
  keys[i] = ~0ull;
  __syncthreads();
  atomicAdd(&cnt[sc[i]], 1);
  __syncthreads();
  if (i == 0) { int a = 0; for (int j = 0; j < 8; ++j) { base[j] = a; a += cnt[j]; } base[8] = a; }
  __syncthreads();
  const int ci = sc[i];
  int rank = 0;
  for (int j = 0; j < i; ++j) rank += (sc[j] == ci) ? 1 : 0;
  perm[base[ci] + rank] = i;
  if (i < 9) off[i] = base[i];
}

// per-class GEMM tile (64 samples x 128 codes, K=4096) + packed argmin
__global__ __launch_bounds__(256) void vq_kernel(
    const float* __restrict__ zE, const float* __restrict__ E,
    const float* __restrict__ norms, const int* __restrict__ perm,
    const int* __restrict__ off, unsigned long long* __restrict__ keys)
{
  const int cls = blockIdx.x;     // 8
  const int mb  = blockIdx.y;     // 8
  const int kb  = blockIdx.z;     // 16
  const int s0 = off[cls];
  const int total = off[cls+1] - s0;
  int nrows = total - mb*64;
  if (nrows <= 0) return;
  if (nrows > 64) nrows = 64;

  __shared__ float sA[64][17];
  __shared__ float sB[128][17];
  __shared__ int srow[64];
  __shared__ unsigned long long skey[64][17];

  const int tid = threadIdx.x;
  const int tx = tid & 15, ty = tid >> 4;
  if (tid < 64) srow[tid] = (tid < nrows) ? perm[s0 + mb*64 + tid] : -1;
  __syncthreads();

  float acc[4][8];
#pragma unroll
  for (int i = 0; i < 4; ++i)
#pragma unroll
    for (int j = 0; j < 8; ++j) acc[i][j] = 0.f;

  const int code0 = cls*2048 + kb*128;
  for (int k0 = 0; k0 < 4096; k0 += 16) {
#pragma unroll
    for (int q = 0; q < 4; ++q) {
      int idx = tid + q*256;
      int r = idx >> 4, kk = idx & 15;
      int s = srow[r];
      sA[r][kk] = (s >= 0) ? zE[(size_t)s*4096 + k0 + kk] : 0.f;
    }
#pragma unroll
    for (int q = 0; q < 8; ++q) {
      int idx = tid + q*256;
      int cb = idx >> 4, kk = idx & 15;
      sB[cb][kk] = E[(size_t)(code0 + cb)*4096 + k0 + kk];
    }
    __syncthreads();
#pragma unroll
    for (int kk = 0; kk < 16; ++kk) {
      float a[4], bv[8];
#pragma unroll
      for (int i = 0; i < 4; ++i) a[i] = sA[ty*4 + i][kk];
#pragma unroll
      for (int j = 0; j < 8; ++j) bv[j] = sB[tx*8 + j][kk];
#pragma unroll
      for (int i = 0; i < 4; ++i)
#pragma unroll
        for (int j = 0; j < 8; ++j) acc[i][j] = fmaf(a[i], bv[j], acc[i][j]);
    }
    __syncthreads();
  }

#pragma unroll
  for (int i = 0; i < 4; ++i) {
    int r = ty*4 + i;
    unsigned long long best = ~0ull;
#pragma unroll
    for (int j = 0; j < 8; ++j) {
      int code = code0 + tx*8 + j;
      float d = norms[code] - 2.f*acc[i][j];
      unsigned u = __float_as_uint(d);
      u = (u & 0x80000000u) ? ~u : (u | 0x80000000u);
      unsigned long long key = ((unsigned long long)u << 32) | (unsigned long long)(unsigned)code;
      if (key < best) best = key;
    }
    skey[r][tx] = best;
  }
  __syncthreads();
  if (tid < 64 && tid < nrows) {
    unsigned long long best = ~0ull;
#pragma unroll
    for (int t = 0; t < 16; ++t) { unsigned long long v = skey[tid][t]; if (v < best) best = v; }
    atomicMin(&keys[srow[tid]], best);
  }
}

__global__ __launch_bounds__(256) void gather_kernel(
    const unsigned long long* __restrict__ keys, const int* __restrict__ perm,
    const float* __restrict__ E, float* __restrict__ zq)
{
  const int i = blockIdx.x;            // permuted output slot
  const int s = perm[i];
  const int code = (int)(unsigned)(keys[s] & 0xFFFFFFFFull);
  const float4* src = (const float4*)(E + (size_t)code*4096);
  float4* dst = (float4*)(zq + (size_t)i*4096);
  for (int t = threadIdx.x; t < 1024; t += 256) dst[t] = src[t];
}

// ================= driver =======================================================
extern "C" void kernel_launch(void* const* d_in, const int* in_sizes, int n_in,
                              void* d_out, int out_size, void* d_ws, size_t ws_size,
                              hipStream_t stream) {
  const float* x   = (const float*)d_in[0];
  const float* We0 = (const float*)d_in[1];
  const float* be0 = (const float*)d_in[2];
  const float* We1 = (const float*)d_in[3];
  const float* be1 = (const float*)d_in[4];
  const float* We2 = (const float*)d_in[5];
  const float* be2 = (const float*)d_in[6];
  const float* E   = (const float*)d_in[7];
  const float* Wd0 = (const float*)d_in[8];
  const float* bd0 = (const float*)d_in[9];
  const float* Wd1 = (const float*)d_in[10];
  const float* bd1 = (const float*)d_in[11];
  const float* Wd2 = (const float*)d_in[12];
  const float* bd2 = (const float*)d_in[13];
  const float* Wo  = (const float*)d_in[14];
  const float* bo  = (const float*)d_in[15];
  const int*   c   = (const int*)d_in[16];

  float* out = (float*)d_out;                     // x_tilde [512,1,28,28] (permuted order)
  float* z_e = out + (size_t)512*784;             // [512,4096]
  float* zq  = z_e + (size_t)512*4096;            // z_q_bar_p [512,4096] == decoder input

  char* ws = (char*)d_ws;
  float* norms = (float*)ws;                                   // 16384 f
  unsigned long long* keys = (unsigned long long*)(ws + 65536);// 512 ull
  int* perm = (int*)(ws + 65536 + 4096);                       // 512 i
  int* offs = (int*)(ws + 65536 + 4096 + 2048);                // 9 i
  float* big = (float*)(ws + 73728);
  size_t avail = (ws_size > 73728) ? (ws_size - 73728) : 0;

  // per-image fp32 bytes across all chunk buffers: 256*4*(196+49+64+64+256+196+784+784)
  int NB = 512;
  while (NB > 1 && (size_t)NB * 2450432ull > avail) NB >>= 1;
  const int nch = 512 / NB;

  size_t o = 0;
  float* h0 = big + o; o += (size_t)NB*256*196;
  float* h1 = big + o; o += (size_t)NB*256*49;
  float* u0 = big + o; o += (size_t)NB*256*64;
  float* a0 = big + o; o += (size_t)NB*256*64;
  float* u1 = big + o; o += (size_t)NB*256*256;
  float* a1 = big + o; o += (size_t)NB*256*196;
  float* u2 = big + o; o += (size_t)NB*256*784;
  float* a2 = big + o; o += (size_t)NB*256*784;

  // ---- encoder (chunked) ----
  for (int ch = 0; ch < nch; ++ch) {
    conv_e0_kernel<<<NB, 256, 0, stream>>>(x + (size_t)ch*NB*784, We0, be0, h0);
    conv3x3_kernel<8,4,2,1,14,14,7,7,1><<<dim3(NB,2,1), 256, 0, stream>>>(h0, We1, be1, h1);
    conv3x3_kernel<8,1,2,1,7,7,4,4,0><<<dim3(NB,2,1), 256, 0, stream>>>(h1, We2, be2,
                                                                        z_e + (size_t)ch*NB*4096);
  }
  // ---- VQ ----
  enorm_kernel<<<16384, 256, 0, stream>>>(E, norms);
  perm_kernel<<<1, 512, 0, stream>>>(c, perm, offs, keys);
  vq_kernel<<<dim3(8,8,16), 256, 0, stream>>>(z_e, E, norms, perm, offs, keys);
  gather_kernel<<<512, 256, 0, stream>>>(keys, perm, E, zq);
  // ---- decoder (chunked, consumes permuted zq straight from d_out) ----
  for (int ch = 0; ch < nch; ++ch) {
    const float* zin = zq + (size_t)ch*NB*4096;   // [NB,256,4,4]
    const int t0 = NB*256*64, t1 = NB*256*256, t2 = NB*256*784;
    upsample2_kernel<4,4><<<CDIV(t0,256), 256, 0, stream>>>(zin, u0, t0);
    conv3x3_kernel<8,4,1,1,8,8,8,8,1><<<dim3(NB,2,1), 256, 0, stream>>>(u0, Wd0, bd0, a0);
    upsample2_kernel<8,8><<<CDIV(t1,256), 256, 0, stream>>>(a0, u1, t1);
    conv3x3_kernel<8,8,1,0,16,16,14,14,1><<<dim3(NB,2,2), 256, 0, stream>>>(u1, Wd1, bd1, a1);
    upsample2_kernel<14,14><<<CDIV(t2,256), 256, 0, stream>>>(a1, u2, t2);
    conv3x3_kernel<8,8,1,1,28,28,28,28,1><<<dim3(NB,2,7), 256, 0, stream>>>(u2, Wd2, bd2, a2);
    conv_out_kernel<<<NB, 256, 0, stream>>>(a2, Wo, bo, out + (size_t)ch*NB*784);
  }
}

// Round 2
// 4881.736 us; speedup vs baseline: 6.0747x; 6.0747x over previous
//
#include <hip/hip_runtime.h>
#include <hip/hip_bf16.h>
#include <cstdint>
#include <cstddef>

#define CDIV(a,b) (((a)+(b)-1)/(b))

typedef __attribute__((ext_vector_type(8))) short vbf8;
typedef __attribute__((ext_vector_type(4))) float vf4;

__device__ inline unsigned short f2bf(float f) {
  unsigned u = __float_as_uint(f);
  unsigned r = (u + 0x7fffu + ((u >> 16) & 1u)) >> 16;
  return (unsigned short)r;
}
__device__ inline float bf2f(unsigned short h) { return __uint_as_float(((unsigned)h) << 16); }

// ================= encoder conv0: 1->256, 28->14, stride2 pad1, relu ============
__global__ __launch_bounds__(256) void conv_e0_kernel(
    const float* __restrict__ x, const float* __restrict__ W,
    const float* __restrict__ b, float* __restrict__ out)
{
  __shared__ float s_img[784];
  const int n = blockIdx.x;
  const int co = threadIdx.x;
  for (int i = threadIdx.x; i < 784; i += 256) s_img[i] = x[(size_t)n*784 + i];
  float w[9];
#pragma unroll
  for (int t = 0; t < 9; ++t) w[t] = W[co*9 + t];
  const float bb = b[co];
  __syncthreads();
  float* orow = out + ((size_t)n*256 + co)*196;
  for (int p = 0; p < 196; ++p) {
    int y = p / 14, xo = p % 14;
    float a = bb;
#pragma unroll
    for (int t = 0; t < 9; ++t) {
      int yi = 2*y + t/3 - 1, xi = 2*xo + t%3 - 1;
      if (yi >= 0 && yi < 28 && xi >= 0 && xi < 28) a = fmaf(w[t], s_img[yi*28 + xi], a);
    }
    orow[p] = fmaxf(a, 0.f);
  }
}

// ================= fp32 256->256 3x3 conv (encoder only now) ====================
template<int TO, int TP, int STRIDE, int PAD, int HIN, int WIN, int HOUT, int WOUT, int ACT>
__global__ __launch_bounds__(256) void conv3x3_kernel(
    const float* __restrict__ in, const float* __restrict__ W,
    const float* __restrict__ bias, float* __restrict__ out)
{
  constexpr int TX = 16;
  constexpr int BLK_CO = TX * TO;
  constexpr int BLK_P  = 16 * TP;
  constexpr int PTR_ = ((BLK_P / WOUT) < HOUT) ? (BLK_P / WOUT) : HOUT;
  constexpr int NPOS = PTR_ * WOUT;
  constexpr int RIN = (PTR_ - 1) * STRIDE + 3;
  constexpr int WS  = (WOUT - 1) * STRIDE + 3;
  constexpr int CIC = 8;
  constexpr int CIN = 256;

  __shared__ float s_in[CIC * RIN * WS];
  __shared__ float s_w[TO * 9 * CIC * 17];   // stride 17: conflict-free writes AND reads

  const int n   = blockIdx.x;
  const int cob = blockIdx.y * BLK_CO;
  const int oy0 = blockIdx.z * PTR_;

  const int tid = threadIdx.x;
  const int tx = tid & 15;
  const int ty = tid >> 4;

  int  boff[TP]; int px_[TP]; int pyg[TP]; bool val[TP];
#pragma unroll
  for (int j = 0; j < TP; ++j) {
    int p = ty * TP + j;
    int yl = p / WOUT, xx = p % WOUT;
    val[j] = (p < NPOS) && (oy0 + yl < HOUT);
    px_[j] = xx;
    pyg[j] = oy0 + yl;
    boff[j] = (p < NPOS) ? (yl * STRIDE * WS + xx * STRIDE) : 0;
  }

  float acc[TO][TP];
#pragma unroll
  for (int i = 0; i < TO; ++i)
#pragma unroll
    for (int j = 0; j < TP; ++j) acc[i][j] = 0.f;

  for (int ci0 = 0; ci0 < CIN; ci0 += CIC) {
    for (int idx = tid; idx < CIC*RIN*WS; idx += 256) {
      int ci  = idx / (RIN*WS);
      int rem = idx % (RIN*WS);
      int r = rem / WS, cc = rem % WS;
      int yi = oy0*STRIDE + r - PAD;
      int xi = cc - PAD;
      float v = 0.f;
      if (yi >= 0 && yi < HIN && xi >= 0 && xi < WIN)
        v = in[((size_t)n*CIN + ci0 + ci)*(HIN*WIN) + yi*WIN + xi];
      s_in[idx] = v;
    }
    for (int idx = tid; idx < BLK_CO*CIC*9; idx += 256) {
      int col = idx / 72;
      int rem = idx % 72;
      float v = W[((size_t)(cob + col)*CIN + ci0)*9 + rem];
      int txw = col / TO, iw = col % TO;
      s_w[(iw*72 + rem)*17 + txw] = v;
    }
    __syncthreads();
#pragma unroll
    for (int ci = 0; ci < CIC; ++ci) {
#pragma unroll
      for (int t = 0; t < 9; ++t) {
        const int kyws = (t/3)*WS + (t%3);
        float wv[TO];
#pragma unroll
        for (int i = 0; i < TO; ++i) wv[i] = s_w[(i*72 + ci*9 + t)*17 + tx];
        float iv[TP];
#pragma unroll
        for (int j = 0; j < TP; ++j) iv[j] = s_in[ci*(RIN*WS) + boff[j] + kyws];
#pragma unroll
        for (int i = 0; i < TO; ++i)
#pragma unroll
          for (int j = 0; j < TP; ++j) acc[i][j] = fmaf(wv[i], iv[j], acc[i][j]);
      }
    }
    __syncthreads();
  }

#pragma unroll
  for (int i = 0; i < TO; ++i) {
    const int co = cob + tx*TO + i;
    const float bb = bias[co];
#pragma unroll
    for (int j = 0; j < TP; ++j) {
      if (!val[j]) continue;
      float v = acc[i][j] + bb;
      if (ACT == 1) v = fmaxf(v, 0.f);
      out[((size_t)n*256 + co)*(HOUT*WOUT) + pyg[j]*WOUT + px_[j]] = v;
    }
  }
}

// ================= weight prep: W[co][ci][9] f32 -> Wt[t][cig][co][8] bf16 ======
__global__ __launch_bounds__(256) void wprep_kernel(
    const float* __restrict__ W, unsigned short* __restrict__ Wt)
{
  int idx = blockIdx.x*256 + threadIdx.x;
  if (idx >= 589824) return;
  int j   = idx & 7;
  int co  = (idx >> 3) & 255;
  int cig = (idx >> 11) & 31;
  int t   = idx >> 16;
  int ci  = cig*8 + j;
  Wt[idx] = f2bf(W[((size_t)co*256 + ci)*9 + t]);
}

// ================= bf16 MFMA 3x3 conv, channel-last =============================
// in [n][HI][WI][256] bf16, Wt [9][32][256] vbf8, out [n][HO][WO][256] bf16
template<int HO, int WO, int WOP, int ROWS, int HI, int WI, int PAD, int ACT>
__global__ __launch_bounds__(256, 2) void convmfma_kernel(
    const unsigned short* __restrict__ inT, const vbf8* __restrict__ Wt,
    const float* __restrict__ bias, unsigned short* __restrict__ outT)
{
  constexpr int NFM = ROWS*WOP/16;
  constexpr int RIN = ROWS + 2;
  constexpr int WS  = WOP + 2;
  __shared__ vbf8 sA[RIN*WS*8];

  const int n  = blockIdx.x;
  const int y0 = blockIdx.y * ROWS;
  const int tid = threadIdx.x;
  const int lane = tid & 63;
  const int wv = tid >> 6;
  const int l15 = lane & 15;
  const int lq  = lane >> 4;
  const int cobase = wv * 64;

  int abase[NFM];
#pragma unroll
  for (int mf = 0; mf < NFM; ++mf) {
    int pos = mf*16 + l15;
    abase[mf] = (pos / WOP) * WS + (pos % WOP);
  }

  vf4 acc[NFM][4];
#pragma unroll
  for (int mf = 0; mf < NFM; ++mf)
#pragma unroll
    for (int nf = 0; nf < 4; ++nf) acc[mf][nf] = (vf4){0.f, 0.f, 0.f, 0.f};

  for (int cc = 0; cc < 4; ++cc) {
    for (int idx = tid; idx < RIN*WS*8; idx += 256) {
      int lin = idx >> 3, cig = idx & 7;
      int r = lin / WS, x = lin % WS;
      int yi = y0 + r - PAD, xi = x - PAD;
      vbf8 v = {0,0,0,0,0,0,0,0};
      if (yi >= 0 && yi < HI && xi >= 0 && xi < WI)
        v = *(const vbf8*)(inT + ((((size_t)n*HI + yi)*WI + xi)*256 + cc*64 + cig*8));
      sA[(lin*8 + cig) ^ (lin & 7)] = v;
    }
    __syncthreads();
#pragma unroll
    for (int t = 0; t < 9; ++t) {
      const int dy = t/3, dx = t%3;
#pragma unroll
      for (int kk = 0; kk < 2; ++kk) {
        vbf8 bfr[4];
        const int cig_g = cc*8 + kk*4 + lq;
#pragma unroll
        for (int nf = 0; nf < 4; ++nf)
          bfr[nf] = Wt[((size_t)t*32 + cig_g)*256 + cobase + nf*16 + l15];
        vbf8 af[NFM];
        const int cigl = kk*4 + lq;
#pragma unroll
        for (int mf = 0; mf < NFM; ++mf) {
          int lin = abase[mf] + dy*WS + dx;
          af[mf] = sA[(lin*8 + cigl) ^ (lin & 7)];
        }
#pragma unroll
        for (int mf = 0; mf < NFM; ++mf)
#pragma unroll
          for (int nf = 0; nf < 4; ++nf)
            acc[mf][nf] = __builtin_amdgcn_mfma_f32_16x16x32_bf16(af[mf], bfr[nf], acc[mf][nf], 0, 0, 0);
      }
    }
    __syncthreads();
  }

  float bb[4];
#pragma unroll
  for (int nf = 0; nf < 4; ++nf) bb[nf] = bias[cobase + nf*16 + l15];
#pragma unroll
  for (int mf = 0; mf < NFM; ++mf) {
#pragma unroll
    for (int q = 0; q < 4; ++q) {
      int pos = mf*16 + lq*4 + q;
      int y = y0 + pos/WOP, x = pos % WOP;
      if (WOP > WO && x >= WO) continue;
      if (HO % ROWS != 0 && y >= HO) continue;
#pragma unroll
      for (int nf = 0; nf < 4; ++nf) {
        float v = acc[mf][nf][q] + bb[nf];
        if (ACT) v = fmaxf(v, 0.f);
        outT[(((size_t)n*HO + y)*WO + x)*256 + cobase + nf*16 + l15] = f2bf(v);
      }
    }
  }
}

// ================= bilinear x2 upsample, channel-last bf16 ======================
template<int H, int W>
__global__ __launch_bounds__(256) void upsample_cl_kernel(
    const unsigned short* __restrict__ in, unsigned short* __restrict__ out, int nimg)
{
  constexpr int Ho = 2*H, Wo = 2*W;
  int idx = blockIdx.x*256 + threadIdx.x;
  int total = nimg * Ho * Wo * 32;
  if (idx >= total) return;
  int cig = idx & 31; int rest = idx >> 5;
  int xo = rest % Wo; rest /= Wo;
  int yo = rest % Ho; int n = rest / Ho;
  float ys = (float)(yo*(H-1)) / (float)(Ho-1);
  float xs = (float)(xo*(W-1)) / (float)(Wo-1);
  int ya = (int)ys; int yb = (ya+1 < H) ? ya+1 : H-1;
  int xa = (int)xs; int xb = (xa+1 < W) ? xa+1 : W-1;
  float wy = ys - (float)ya, wx = xs - (float)xa;
  const unsigned short* base = in + (size_t)n*H*W*256 + cig*8;
  vbf8 vaa = *(const vbf8*)(base + ((size_t)ya*W + xa)*256);
  vbf8 vab = *(const vbf8*)(base + ((size_t)ya*W + xb)*256);
  vbf8 vba = *(const vbf8*)(base + ((size_t)yb*W + xa)*256);
  vbf8 vbb = *(const vbf8*)(base + ((size_t)yb*W + xb)*256);
  vbf8 o;
#pragma unroll
  for (int j = 0; j < 8; ++j) {
    float r0 = bf2f((unsigned short)vaa[j])*(1.f-wy) + bf2f((unsigned short)vba[j])*wy;
    float r1 = bf2f((unsigned short)vab[j])*(1.f-wy) + bf2f((unsigned short)vbb[j])*wy;
    o[j] = (short)f2bf(r0*(1.f-wx) + r1*wx);
  }
  *(vbf8*)(out + (((size_t)n*Ho + yo)*Wo + xo)*256 + cig*8) = o;
}

// ================= output conv: 256->1, 3x3 pad1, sigmoid (channel-last) =======
__global__ __launch_bounds__(256) void conv_out_t_kernel(
    const unsigned short* __restrict__ a2t, const float* __restrict__ Wo,
    const float* __restrict__ bo, float* __restrict__ out)
{
  const int n = blockIdx.x;
  const int y0 = blockIdx.y * 14;
  const int tid = threadIdx.x;
  __shared__ vbf8 s_in[16*30*8];   // rows y0-1 .. y0+14, cols -1..28, 64 ci, swizzled
  __shared__ float s_w[9*64];
  float acc[2] = {0.f, 0.f};
  for (int cc = 0; cc < 4; ++cc) {
    for (int idx = tid; idx < 16*30*8; idx += 256) {
      int lin = idx >> 3, cig = idx & 7;
      int r = lin / 30, xx = lin % 30;
      int yi = y0 + r - 1, xi = xx - 1;
      vbf8 v = {0,0,0,0,0,0,0,0};
      if (yi >= 0 && yi < 28 && xi >= 0 && xi < 28)
        v = *(const vbf8*)(a2t + (((size_t)n*28 + yi)*28 + xi)*256 + cc*64 + cig*8);
      s_in[(lin*8 + cig) ^ (lin & 7)] = v;
    }
    for (int idx = tid; idx < 576; idx += 256) {
      int t = idx / 64, cil = idx % 64;
      s_w[t*64 + cil] = Wo[((size_t)cc*64 + cil)*9 + t];
    }
    __syncthreads();
#pragma unroll
    for (int q = 0; q < 2; ++q) {
      int p = tid + q*256;
      if (p < 392) {
        int y = p / 28, x = p % 28;
        float a = acc[q];
#pragma unroll
        for (int t = 0; t < 9; ++t) {
          int lin = (y + t/3)*30 + (x + t%3);
#pragma unroll
          for (int cig = 0; cig < 8; ++cig) {
            vbf8 v = s_in[(lin*8 + cig) ^ (lin & 7)];
#pragma unroll
            for (int j = 0; j < 8; ++j)
              a = fmaf(bf2f((unsigned short)v[j]), s_w[t*64 + cig*8 + j], a);
          }
        }
        acc[q] = a;
      }
    }
    __syncthreads();
  }
  const float bb = bo[0];
  for (int q = 0; q < 2; ++q) {
    int p = tid + q*256;
    if (p < 392) {
      int y = y0 + p/28, x = p%28;
      out[(size_t)n*784 + y*28 + x] = 1.f/(1.f + expf(-(acc[q] + bb)));
    }
  }
}

// ================= VQ pieces ====================================================
__global__ __launch_bounds__(256) void enorm_kernel(
    const float* __restrict__ E, float* __restrict__ norms)
{
  const int k = blockIdx.x;
  const float4* row = (const float4*)(E + (size_t)k*4096);
  float s = 0.f;
  for (int i = threadIdx.x; i < 1024; i += 256) {
    float4 v = row[i];
    s += v.x*v.x + v.y*v.y + v.z*v.z + v.w*v.w;
  }
  __shared__ float red[256];
  red[threadIdx.x] = s; __syncthreads();
  for (int off = 128; off > 0; off >>= 1) {
    if (threadIdx.x < off) red[threadIdx.x] += red[threadIdx.x + off];
    __syncthreads();
  }
  if (threadIdx.x == 0) norms[k] = red[0];
}

__global__ __launch_bounds__(512) void perm_kernel(
    const int* __restrict__ c, int* __restrict__ perm, int* __restrict__ off,
    unsigned long long* __restrict__ keys)
{
  __shared__ int sc[512];
  __shared__ int cnt[8];
  __shared__ int base[9];
  const int i = threadIdx.x;
  sc[i] = c[i];
  if (i < 8) cnt[i] = 0;
  keys[i] = ~0ull;
  __syncthreads();
  atomicAdd(&cnt[sc[i]], 1);
  __syncthreads();
  if (i == 0) { int a = 0; for (int j = 0; j < 8; ++j) { base[j] = a; a += cnt[j]; } base[8] = a; }
  __syncthreads();
  const int ci = sc[i];
  int rank = 0;
  for (int j = 0; j < i; ++j) rank += (sc[j] == ci) ? 1 : 0;
  perm[base[ci] + rank] = i;
  if (i < 9) off[i] = base[i];
}

__global__ __launch_bounds__(256) void vq_kernel(
    const float* __restrict__ zE, const float* __restrict__ E,
    const float* __restrict__ norms, const int* __restrict__ perm,
    const int* __restrict__ off, unsigned long long* __restrict__ keys)
{
  const int cls = blockIdx.x;
  const int mb  = blockIdx.y;
  const int kb  = blockIdx.z;
  const int s0 = off[cls];
  const int total = off[cls+1] - s0;
  int nrows = total - mb*64;
  if (nrows <= 0) return;
  if (nrows > 64) nrows = 64;

  __shared__ float sA[64][17];
  __shared__ float sB[128][17];
  __shared__ int srow[64];
  __shared__ unsigned long long skey[64][17];

  const int tid = threadIdx.x;
  const int tx = tid & 15, ty = tid >> 4;
  if (tid < 64) srow[tid] = (tid < nrows) ? perm[s0 + mb*64 + tid] : -1;
  __syncthreads();

  float acc[4][8];
#pragma unroll
  for (int i = 0; i < 4; ++i)
#pragma unroll
    for (int j = 0; j < 8; ++j) acc[i][j] = 0.f;

  const int code0 = cls*2048 + kb*128;
  for (int k0 = 0; k0 < 4096; k0 += 16) {
#pragma unroll
    for (int q = 0; q < 4; ++q) {
      int idx = tid + q*256;
      int r = idx >> 4, kk = idx & 15;
      int s = srow[r];
      sA[r][kk] = (s >= 0) ? zE[(size_t)s*4096 + k0 + kk] : 0.f;
    }
#pragma unroll
    for (int q = 0; q < 8; ++q) {
      int idx = tid + q*256;
      int cb = idx >> 4, kk = idx & 15;
      sB[cb][kk] = E[(size_t)(code0 + cb)*4096 + k0 + kk];
    }
    __syncthreads();
#pragma unroll
    for (int kk = 0; kk < 16; ++kk) {
      float a[4], bv[8];
#pragma unroll
      for (int i = 0; i < 4; ++i) a[i] = sA[ty*4 + i][kk];
#pragma unroll
      for (int j = 0; j < 8; ++j) bv[j] = sB[tx*8 + j][kk];
#pragma unroll
      for (int i = 0; i < 4; ++i)
#pragma unroll
        for (int j = 0; j < 8; ++j) acc[i][j] = fmaf(a[i], bv[j], acc[i][j]);
    }
    __syncthreads();
  }

#pragma unroll
  for (int i = 0; i < 4; ++i) {
    int r = ty*4 + i;
    unsigned long long best = ~0ull;
#pragma unroll
    for (int j = 0; j < 8; ++j) {
      int code = code0 + tx*8 + j;
      float d = norms[code] - 2.f*acc[i][j];
      unsigned u = __float_as_uint(d);
      u = (u & 0x80000000u) ? ~u : (u | 0x80000000u);
      unsigned long long key = ((unsigned long long)u << 32) | (unsigned long long)(unsigned)code;
      if (key < best) best = key;
    }
    skey[r][tx] = best;
  }
  __syncthreads();
  if (tid < 64 && tid < nrows) {
    unsigned long long best = ~0ull;
#pragma unroll
    for (int t = 0; t < 16; ++t) { unsigned long long v = skey[tid][t]; if (v < best) best = v; }
    atomicMin(&keys[srow[tid]], best);
  }
}

// gather: zq fp32 (output, channel-major) + zqt bf16 (channel-last for decoder)
__global__ __launch_bounds__(256) void gather_t_kernel(
    const unsigned long long* __restrict__ keys, const int* __restrict__ perm,
    const float* __restrict__ E, float* __restrict__ zq, unsigned short* __restrict__ zqt)
{
  const int i = blockIdx.x;
  const int s = perm[i];
  const int code = (int)(unsigned)(keys[s] & 0xFFFFFFFFull);
  const float4* src = (const float4*)(E + (size_t)code*4096);
  float4* dst = (float4*)(zq + (size_t)i*4096);
  for (int t = threadIdx.x; t < 1024; t += 256) {
    float4 v = src[t];
    dst[t] = v;
    int e0 = t*4;
    int ci = e0 >> 4, sp = e0 & 15;
    unsigned short* zp = zqt + ((size_t)i*16 + sp)*256 + ci;
    zp[0]   = f2bf(v.x);
    zp[256] = f2bf(v.y);
    zp[512] = f2bf(v.z);
    zp[768] = f2bf(v.w);
  }
}

// ================= driver =======================================================
extern "C" void kernel_launch(void* const* d_in, const int* in_sizes, int n_in,
                              void* d_out, int out_size, void* d_ws, size_t ws_size,
                              hipStream_t stream) {
  const float* x   = (const float*)d_in[0];
  const float* We0 = (const float*)d_in[1];
  const float* be0 = (const float*)d_in[2];
  const float* We1 = (const float*)d_in[3];
  const float* be1 = (const float*)d_in[4];
  const float* We2 = (const float*)d_in[5];
  const float* be2 = (const float*)d_in[6];
  const float* E   = (const float*)d_in[7];
  const float* Wd0 = (const float*)d_in[8];
  const float* bd0 = (const float*)d_in[9];
  const float* Wd1 = (const float*)d_in[10];
  const float* bd1 = (const float*)d_in[11];
  const float* Wd2 = (const float*)d_in[12];
  const float* bd2 = (const float*)d_in[13];
  const float* Wo  = (const float*)d_in[14];
  const float* bo  = (const float*)d_in[15];
  const int*   c   = (const int*)d_in[16];

  float* out = (float*)d_out;
  float* z_e = out + (size_t)512*784;
  float* zq  = z_e + (size_t)512*4096;

  char* ws = (char*)d_ws;
  size_t off = 0;
  float* norms = (float*)(ws + off); off += 65536;
  unsigned long long* keys = (unsigned long long*)(ws + off); off += 4096;
  int* perm = (int*)(ws + off); off += 2048;
  int* offs = (int*)(ws + off); off += 256;
  unsigned short* zqt = (unsigned short*)(ws + off); off += (size_t)512*16*256*2;
  unsigned short* Wt0 = (unsigned short*)(ws + off); off += 1179648;
  unsigned short* Wt1 = (unsigned short*)(ws + off); off += 1179648;
  unsigned short* Wt2 = (unsigned short*)(ws + off); off += 1179648;
  char* big = ws + off;
  size_t avail = (ws_size > off) ? ws_size - off : 0;

  // per-image bytes: h0 200704 + h1 50176 (f32) + bf16: u0t 32768 + a0t 32768 +
  // u1t 131072 + a1t 100352 + u2t 401408 + a2t 401408 = 1350656
  int NB = 512;
  while (NB > 1 && (size_t)NB * 1350656ull > avail) NB >>= 1;
  const int nch = 512 / NB;

  size_t o = 0;
  float* h0 = (float*)(big + o); o += (size_t)NB*200704;
  float* h1 = (float*)(big + o); o += (size_t)NB*50176;
  unsigned short* u0t = (unsigned short*)(big + o); o += (size_t)NB*32768;
  unsigned short* a0t = (unsigned short*)(big + o); o += (size_t)NB*32768;
  unsigned short* u1t = (unsigned short*)(big + o); o += (size_t)NB*131072;
  unsigned short* a1t = (unsigned short*)(big + o); o += (size_t)NB*100352;
  unsigned short* u2t = (unsigned short*)(big + o); o += (size_t)NB*401408;
  unsigned short* a2t = (unsigned short*)(big + o); o += (size_t)NB*401408;

  // ---- weight prep + codebook norms ----
  wprep_kernel<<<CDIV(589824,256), 256, 0, stream>>>(Wd0, Wt0);
  wprep_kernel<<<CDIV(589824,256), 256, 0, stream>>>(Wd1, Wt1);
  wprep_kernel<<<CDIV(589824,256), 256, 0, stream>>>(Wd2, Wt2);
  enorm_kernel<<<16384, 256, 0, stream>>>(E, norms);

  // ---- encoder (fp32, chunked) ----
  for (int ch = 0; ch < nch; ++ch) {
    conv_e0_kernel<<<NB, 256, 0, stream>>>(x + (size_t)ch*NB*784, We0, be0, h0);
    conv3x3_kernel<8,4,2,1,14,14,7,7,1><<<dim3(NB,2,1), 256, 0, stream>>>(h0, We1, be1, h1);
    conv3x3_kernel<8,1,2,1,7,7,4,4,0><<<dim3(NB,2,1), 256, 0, stream>>>(h1, We2, be2,
                                                                        z_e + (size_t)ch*NB*4096);
  }
  // ---- VQ (fp32) ----
  perm_kernel<<<1, 512, 0, stream>>>(c, perm, offs, keys);
  vq_kernel<<<dim3(8,8,16), 256, 0, stream>>>(z_e, E, norms, perm, offs, keys);
  gather_t_kernel<<<512, 256, 0, stream>>>(keys, perm, E, zq, zqt);

  // ---- decoder (bf16 MFMA, channel-last, chunked) ----
  for (int ch = 0; ch < nch; ++ch) {
    const unsigned short* zt = zqt + (size_t)ch*NB*16*256;
    upsample_cl_kernel<4,4><<<CDIV(NB*2048,256), 256, 0, stream>>>(zt, u0t, NB);
    convmfma_kernel<8,8,8,8, 8,8,1,1><<<dim3(NB,1), 256, 0, stream>>>(
        u0t, (const vbf8*)Wt0, bd0, a0t);
    upsample_cl_kernel<8,8><<<CDIV(NB*8192,256), 256, 0, stream>>>(a0t, u1t, NB);
    convmfma_kernel<14,14,16,4, 16,16,0,1><<<dim3(NB,4), 256, 0, stream>>>(
        u1t, (const vbf8*)Wt1, bd1, a1t);
    upsample_cl_kernel<14,14><<<CDIV(NB*25088,256), 256, 0, stream>>>(a1t, u2t, NB);
    convmfma_kernel<28,28,28,4, 28,28,1,1><<<dim3(NB,7), 256, 0, stream>>>(
        u2t, (const vbf8*)Wt2, bd2, a2t);
    conv_out_t_kernel<<<dim3(NB,2), 256, 0, stream>>>(a2t, Wo, bo, out + (size_t)ch*NB*784);
  }
}

// Round 3
// 2990.488 us; speedup vs baseline: 9.9165x; 1.6324x over previous
//
#include <hip/hip_runtime.h>
#include <hip/hip_bf16.h>
#include <cstdint>
#include <cstddef>

#define CDIV(a,b) (((a)+(b)-1)/(b))

typedef __attribute__((ext_vector_type(8))) short vbf8;
typedef __attribute__((ext_vector_type(4))) float vf4;

__device__ inline unsigned short f2bf(float f) {
  unsigned u = __float_as_uint(f);
  unsigned r = (u + 0x7fffu + ((u >> 16) & 1u)) >> 16;
  return (unsigned short)r;
}
__device__ inline float bf2f(unsigned short h) { return __uint_as_float(((unsigned)h) << 16); }

// ============ encoder conv0: 1->256, 28->14, s2 p1, relu, ch-last hi/lo ========
__global__ __launch_bounds__(256) void conv_e0_cl_kernel(
    const float* __restrict__ x, const float* __restrict__ W,
    const float* __restrict__ b, unsigned short* __restrict__ hi,
    unsigned short* __restrict__ lo)
{
  __shared__ float s_img[784];
  const int n = blockIdx.x;
  const int co = threadIdx.x;
  for (int i = threadIdx.x; i < 784; i += 256) s_img[i] = x[(size_t)n*784 + i];
  float w[9];
#pragma unroll
  for (int t = 0; t < 9; ++t) w[t] = W[co*9 + t];
  const float bb = b[co];
  __syncthreads();
  for (int p = 0; p < 196; ++p) {
    int y = p / 14, xo = p % 14;
    float a = bb;
#pragma unroll
    for (int t = 0; t < 9; ++t) {
      int yi = 2*y + t/3 - 1, xi = 2*xo + t%3 - 1;
      if (yi >= 0 && yi < 28 && xi >= 0 && xi < 28) a = fmaf(w[t], s_img[yi*28 + xi], a);
    }
    a = fmaxf(a, 0.f);
    unsigned short h = f2bf(a);
    size_t oidx = ((size_t)n*196 + p)*256 + co;
    hi[oidx] = h;
    lo[oidx] = f2bf(a - bf2f(h));
  }
}

// ============ weight prep: W[co][ci][9] f32 -> [t][cig][co][8] bf16 hi/lo ======
__global__ __launch_bounds__(256) void wprep2_kernel(
    const float* __restrict__ W, unsigned short* __restrict__ Whi,
    unsigned short* __restrict__ Wlo)
{
  int idx = blockIdx.x*256 + threadIdx.x;
  if (idx >= 589824) return;
  int j   = idx & 7;
  int co  = (idx >> 3) & 255;
  int cig = (idx >> 11) & 31;
  int t   = idx >> 16;
  int ci  = cig*8 + j;
  float w = W[((size_t)co*256 + ci)*9 + t];
  unsigned short h = f2bf(w);
  Whi[idx] = h;
  Wlo[idx] = f2bf(w - bf2f(h));
}

// ============ unified bf16 MFMA 3x3 conv, channel-last =========================
// in [n][HI][WI][256] (hi; + lo plane if SPLIT), Wt [9][32][256] vbf8 (+lo plane)
// OUTMODE: 0 = bf16 ch-last, 1 = bf16 ch-last hi+lo, 2 = fp32 ch-major
template<int STRIDE, int HO, int WO, int WOP, int ROWS, int HI, int WI, int PAD,
         int ACT, int SPLIT, int OUTMODE>
__global__ __launch_bounds__(256, 2) void convmfma_kernel(
    const unsigned short* __restrict__ inT, const unsigned short* __restrict__ inTlo,
    const vbf8* __restrict__ Wt, const vbf8* __restrict__ Wtlo,
    const float* __restrict__ bias,
    unsigned short* __restrict__ outT, unsigned short* __restrict__ outTlo,
    float* __restrict__ outF)
{
  constexpr int NFM = ROWS*WOP/16;
  constexpr int RIN = (ROWS-1)*STRIDE + 3;
  constexpr int WS  = (WOP-1)*STRIDE + 3;
  constexpr int NG  = SPLIT ? 12 : 4;
  __shared__ vbf8 sA[RIN*WS*8];

  const int n  = blockIdx.x;
  const int y0 = blockIdx.y * ROWS;
  const int tid = threadIdx.x;
  const int lane = tid & 63;
  const int wv = tid >> 6;
  const int l15 = lane & 15;
  const int lq  = lane >> 4;
  const int cobase = wv * 64;

  int abase[NFM];
#pragma unroll
  for (int mf = 0; mf < NFM; ++mf) {
    int pos = mf*16 + l15;
    abase[mf] = (pos / WOP) * STRIDE * WS + (pos % WOP) * STRIDE;
  }

  vf4 acc[NFM][4];
#pragma unroll
  for (int mf = 0; mf < NFM; ++mf)
#pragma unroll
    for (int nf = 0; nf < 4; ++nf) acc[mf][nf] = (vf4){0.f, 0.f, 0.f, 0.f};

#pragma unroll 1
  for (int g = 0; g < NG; ++g) {
    const int cc = g & 3;
    const unsigned short* src = (SPLIT && g >= 8) ? inTlo : inT;           // A plane
    const vbf8* wsrc = (SPLIT && g >= 4 && g < 8) ? Wtlo : Wt;             // W plane
    for (int idx = tid; idx < RIN*WS*8; idx += 256) {
      int lin = idx >> 3, cig = idx & 7;
      int r = lin / WS, x = lin % WS;
      int yi = y0*STRIDE + r - PAD, xi = x - PAD;
      vbf8 v = {0,0,0,0,0,0,0,0};
      if (yi >= 0 && yi < HI && xi >= 0 && xi < WI)
        v = *(const vbf8*)(src + ((((size_t)n*HI + yi)*WI + xi)*256 + cc*64 + cig*8));
      sA[(lin*8 + cig) ^ (lin & 7)] = v;
    }
    __syncthreads();
#pragma unroll
    for (int t = 0; t < 9; ++t) {
      const int dy = t/3, dx = t%3;
#pragma unroll
      for (int kk = 0; kk < 2; ++kk) {
        vbf8 bfr[4];
        const int cig_g = cc*8 + kk*4 + lq;
#pragma unroll
        for (int nf = 0; nf < 4; ++nf)
          bfr[nf] = wsrc[((size_t)t*32 + cig_g)*256 + cobase + nf*16 + l15];
        vbf8 af[NFM];
        const int cigl = kk*4 + lq;
#pragma unroll
        for (int mf = 0; mf < NFM; ++mf) {
          int lin = abase[mf] + dy*WS + dx;
          af[mf] = sA[(lin*8 + cigl) ^ (lin & 7)];
        }
#pragma unroll
        for (int mf = 0; mf < NFM; ++mf)
#pragma unroll
          for (int nf = 0; nf < 4; ++nf)
            acc[mf][nf] = __builtin_amdgcn_mfma_f32_16x16x32_bf16(af[mf], bfr[nf], acc[mf][nf], 0, 0, 0);
      }
    }
    __syncthreads();
  }

  float bb[4];
#pragma unroll
  for (int nf = 0; nf < 4; ++nf) bb[nf] = bias[cobase + nf*16 + l15];
#pragma unroll
  for (int mf = 0; mf < NFM; ++mf) {
#pragma unroll
    for (int q = 0; q < 4; ++q) {
      int pos = mf*16 + lq*4 + q;
      int y = y0 + pos/WOP, x = pos % WOP;
      if (WOP > WO && x >= WO) continue;
      if (HO % ROWS != 0 && y >= HO) continue;
#pragma unroll
      for (int nf = 0; nf < 4; ++nf) {
        float v = acc[mf][nf][q] + bb[nf];
        if (ACT) v = fmaxf(v, 0.f);
        const int co = cobase + nf*16 + l15;
        if (OUTMODE == 2) {
          outF[((size_t)n*256 + co)*(HO*WO) + (y - 0)*WO + x] = v;
        } else {
          size_t oidx = (((size_t)n*HO + y)*WO + x)*256 + co;
          unsigned short h = f2bf(v);
          outT[oidx] = h;
          if (OUTMODE == 1) outTlo[oidx] = f2bf(v - bf2f(h));
        }
      }
    }
  }
}

// ============ bilinear x2 upsample, channel-last bf16 ==========================
template<int H, int W>
__global__ __launch_bounds__(256) void upsample_cl_kernel(
    const unsigned short* __restrict__ in, unsigned short* __restrict__ out, int nimg)
{
  constexpr int Ho = 2*H, Wo = 2*W;
  int idx = blockIdx.x*256 + threadIdx.x;
  int total = nimg * Ho * Wo * 32;
  if (idx >= total) return;
  int cig = idx & 31; int rest = idx >> 5;
  int xo = rest % Wo; rest /= Wo;
  int yo = rest % Ho; int n = rest / Ho;
  float ys = (float)(yo*(H-1)) / (float)(Ho-1);
  float xs = (float)(xo*(W-1)) / (float)(Wo-1);
  int ya = (int)ys; int yb = (ya+1 < H) ? ya+1 : H-1;
  int xa = (int)xs; int xb = (xa+1 < W) ? xa+1 : W-1;
  float wy = ys - (float)ya, wx = xs - (float)xa;
  const unsigned short* base = in + (size_t)n*H*W*256 + cig*8;
  vbf8 vaa = *(const vbf8*)(base + ((size_t)ya*W + xa)*256);
  vbf8 vab = *(const vbf8*)(base + ((size_t)ya*W + xb)*256);
  vbf8 vba = *(const vbf8*)(base + ((size_t)yb*W + xa)*256);
  vbf8 vbb = *(const vbf8*)(base + ((size_t)yb*W + xb)*256);
  vbf8 o;
#pragma unroll
  for (int j = 0; j < 8; ++j) {
    float r0 = bf2f((unsigned short)vaa[j])*(1.f-wy) + bf2f((unsigned short)vba[j])*wy;
    float r1 = bf2f((unsigned short)vab[j])*(1.f-wy) + bf2f((unsigned short)vbb[j])*wy;
    o[j] = (short)f2bf(r0*(1.f-wx) + r1*wx);
  }
  *(vbf8*)(out + (((size_t)n*Ho + yo)*Wo + xo)*256 + cig*8) = o;
}

// ============ output conv: 256->1, 3x3 pad1, sigmoid (channel-last) ============
__global__ __launch_bounds__(256) void conv_out_t_kernel(
    const unsigned short* __restrict__ a2t, const float* __restrict__ Wo,
    const float* __restrict__ bo, float* __restrict__ out)
{
  const int n = blockIdx.x;
  const int y0 = blockIdx.y * 14;
  const int tid = threadIdx.x;
  __shared__ vbf8 s_in[16*30*8];
  __shared__ float s_w[9*64];
  float acc[2] = {0.f, 0.f};
  for (int cc = 0; cc < 4; ++cc) {
    for (int idx = tid; idx < 16*30*8; idx += 256) {
      int lin = idx >> 3, cig = idx & 7;
      int r = lin / 30, xx = lin % 30;
      int yi = y0 + r - 1, xi = xx - 1;
      vbf8 v = {0,0,0,0,0,0,0,0};
      if (yi >= 0 && yi < 28 && xi >= 0 && xi < 28)
        v = *(const vbf8*)(a2t + (((size_t)n*28 + yi)*28 + xi)*256 + cc*64 + cig*8);
      s_in[(lin*8 + cig) ^ (lin & 7)] = v;
    }
    for (int idx = tid; idx < 576; idx += 256) {
      int t = idx / 64, cil = idx % 64;
      s_w[t*64 + cil] = Wo[((size_t)cc*64 + cil)*9 + t];
    }
    __syncthreads();
#pragma unroll
    for (int q = 0; q < 2; ++q) {
      int p = tid + q*256;
      if (p < 392) {
        int y = p / 28, x = p % 28;
        float a = acc[q];
#pragma unroll
        for (int t = 0; t < 9; ++t) {
          int lin = (y + t/3)*30 + (x + t%3);
#pragma unroll
          for (int cig = 0; cig < 8; ++cig) {
            vbf8 v = s_in[(lin*8 + cig) ^ (lin & 7)];
#pragma unroll
            for (int j = 0; j < 8; ++j)
              a = fmaf(bf2f((unsigned short)v[j]), s_w[t*64 + cig*8 + j], a);
          }
        }
        acc[q] = a;
      }
    }
    __syncthreads();
  }
  const float bb = bo[0];
  for (int q = 0; q < 2; ++q) {
    int p = tid + q*256;
    if (p < 392) {
      int y = y0 + p/28, x = p%28;
      out[(size_t)n*784 + y*28 + x] = 1.f/(1.f + expf(-(acc[q] + bb)));
    }
  }
}

// ============ VQ pieces ========================================================
__global__ __launch_bounds__(256) void enorm_kernel(
    const float* __restrict__ E, float* __restrict__ norms)
{
  const int k = blockIdx.x;
  const float4* row = (const float4*)(E + (size_t)k*4096);
  float s = 0.f;
  for (int i = threadIdx.x; i < 1024; i += 256) {
    float4 v = row[i];
    s += v.x*v.x + v.y*v.y + v.z*v.z + v.w*v.w;
  }
  __shared__ float red[256];
  red[threadIdx.x] = s; __syncthreads();
  for (int off = 128; off > 0; off >>= 1) {
    if (threadIdx.x < off) red[threadIdx.x] += red[threadIdx.x + off];
    __syncthreads();
  }
  if (threadIdx.x == 0) norms[k] = red[0];
}

__global__ __launch_bounds__(512) void perm_kernel(
    const int* __restrict__ c, int* __restrict__ perm, int* __restrict__ off,
    unsigned long long* __restrict__ keys)
{
  __shared__ int sc[512];
  __shared__ int cnt[8];
  __shared__ int base[9];
  const int i = threadIdx.x;
  sc[i] = c[i];
  if (i < 8) cnt[i] = 0;
  keys[i] = ~0ull;
  __syncthreads();
  atomicAdd(&cnt[sc[i]], 1);
  __syncthreads();
  if (i == 0) { int a = 0; for (int j = 0; j < 8; ++j) { base[j] = a; a += cnt[j]; } base[8] = a; }
  __syncthreads();
  const int ci = sc[i];
  int rank = 0;
  for (int j = 0; j < i; ++j) rank += (sc[j] == ci) ? 1 : 0;
  perm[base[ci] + rank] = i;
  if (i < 9) off[i] = base[i];
}

__global__ __launch_bounds__(256) void vq_kernel(
    const float* __restrict__ zE, const float* __restrict__ E,
    const float* __restrict__ norms, const int* __restrict__ perm,
    const int* __restrict__ off, unsigned long long* __restrict__ keys)
{
  const int cls = blockIdx.x;
  const int mb  = blockIdx.y;
  const int kb  = blockIdx.z;
  const int s0 = off[cls];
  const int total = off[cls+1] - s0;
  int nrows = total - mb*64;
  if (nrows <= 0) return;
  if (nrows > 64) nrows = 64;

  __shared__ float sA[64][17];
  __shared__ float sB[128][17];
  __shared__ int srow[64];
  __shared__ unsigned long long skey[64][17];

  const int tid = threadIdx.x;
  const int tx = tid & 15, ty = tid >> 4;
  if (tid < 64) srow[tid] = (tid < nrows) ? perm[s0 + mb*64 + tid] : -1;
  __syncthreads();

  float acc[4][8];
#pragma unroll
  for (int i = 0; i < 4; ++i)
#pragma unroll
    for (int j = 0; j < 8; ++j) acc[i][j] = 0.f;

  const int code0 = cls*2048 + kb*128;
  for (int k0 = 0; k0 < 4096; k0 += 16) {
#pragma unroll
    for (int q = 0; q < 4; ++q) {
      int idx = tid + q*256;
      int r = idx >> 4, kk = idx & 15;
      int s = srow[r];
      sA[r][kk] = (s >= 0) ? zE[(size_t)s*4096 + k0 + kk] : 0.f;
    }
#pragma unroll
    for (int q = 0; q < 8; ++q) {
      int idx = tid + q*256;
      int cb = idx >> 4, kk = idx & 15;
      sB[cb][kk] = E[(size_t)(code0 + cb)*4096 + k0 + kk];
    }
    __syncthreads();
#pragma unroll
    for (int kk = 0; kk < 16; ++kk) {
      float a[4], bv[8];
#pragma unroll
      for (int i = 0; i < 4; ++i) a[i] = sA[ty*4 + i][kk];
#pragma unroll
      for (int j = 0; j < 8; ++j) bv[j] = sB[tx*8 + j][kk];
#pragma unroll
      for (int i = 0; i < 4; ++i)
#pragma unroll
        for (int j = 0; j < 8; ++j) acc[i][j] = fmaf(a[i], bv[j], acc[i][j]);
    }
    __syncthreads();
  }

#pragma unroll
  for (int i = 0; i < 4; ++i) {
    int r = ty*4 + i;
    unsigned long long best = ~0ull;
#pragma unroll
    for (int j = 0; j < 8; ++j) {
      int code = code0 + tx*8 + j;
      float d = norms[code] - 2.f*acc[i][j];
      unsigned u = __float_as_uint(d);
      u = (u & 0x80000000u) ? ~u : (u | 0x80000000u);
      unsigned long long key = ((unsigned long long)u << 32) | (unsigned long long)(unsigned)code;
      if (key < best) best = key;
    }
    skey[r][tx] = best;
  }
  __syncthreads();
  if (tid < 64 && tid < nrows) {
    unsigned long long best = ~0ull;
#pragma unroll
    for (int t = 0; t < 16; ++t) { unsigned long long v = skey[tid][t]; if (v < best) best = v; }
    atomicMin(&keys[srow[tid]], best);
  }
}

__global__ __launch_bounds__(256) void gather_t_kernel(
    const unsigned long long* __restrict__ keys, const int* __restrict__ perm,
    const float* __restrict__ E, float* __restrict__ zq, unsigned short* __restrict__ zqt)
{
  const int i = blockIdx.x;
  const int s = perm[i];
  const int code = (int)(unsigned)(keys[s] & 0xFFFFFFFFull);
  const float4* src = (const float4*)(E + (size_t)code*4096);
  float4* dst = (float4*)(zq + (size_t)i*4096);
  for (int t = threadIdx.x; t < 1024; t += 256) {
    float4 v = src[t];
    dst[t] = v;
    int e0 = t*4;
    int ci = e0 >> 4, sp = e0 & 15;
    unsigned short* zp = zqt + ((size_t)i*16 + sp)*256 + ci;
    zp[0]   = f2bf(v.x);
    zp[256] = f2bf(v.y);
    zp[512] = f2bf(v.z);
    zp[768] = f2bf(v.w);
  }
}

// ============ driver ===========================================================
extern "C" void kernel_launch(void* const* d_in, const int* in_sizes, int n_in,
                              void* d_out, int out_size, void* d_ws, size_t ws_size,
                              hipStream_t stream) {
  const float* x   = (const float*)d_in[0];
  const float* We0 = (const float*)d_in[1];
  const float* be0 = (const float*)d_in[2];
  const float* We1 = (const float*)d_in[3];
  const float* be1 = (const float*)d_in[4];
  const float* We2 = (const float*)d_in[5];
  const float* be2 = (const float*)d_in[6];
  const float* E   = (const float*)d_in[7];
  const float* Wd0 = (const float*)d_in[8];
  const float* bd0 = (const float*)d_in[9];
  const float* Wd1 = (const float*)d_in[10];
  const float* bd1 = (const float*)d_in[11];
  const float* Wd2 = (const float*)d_in[12];
  const float* bd2 = (const float*)d_in[13];
  const float* Wo  = (const float*)d_in[14];
  const float* bo  = (const float*)d_in[15];
  const int*   c   = (const int*)d_in[16];

  float* out = (float*)d_out;
  float* z_e = out + (size_t)512*784;
  float* zq  = z_e + (size_t)512*4096;

  char* ws = (char*)d_ws;
  size_t off = 0;
  float* norms = (float*)(ws + off); off += 65536;
  unsigned long long* keys = (unsigned long long*)(ws + off); off += 4096;
  int* perm = (int*)(ws + off); off += 2048;
  int* offs = (int*)(ws + off); off += 256;
  unsigned short* zqt = (unsigned short*)(ws + off); off += (size_t)512*16*256*2;
  unsigned short* Wt0  = (unsigned short*)(ws + off); off += 1179648;
  unsigned short* Wt0l = (unsigned short*)(ws + off); off += 1179648;
  unsigned short* Wt1  = (unsigned short*)(ws + off); off += 1179648;
  unsigned short* Wt1l = (unsigned short*)(ws + off); off += 1179648;
  unsigned short* Wt2  = (unsigned short*)(ws + off); off += 1179648;
  unsigned short* Wt2l = (unsigned short*)(ws + off); off += 1179648;
  unsigned short* We1h = (unsigned short*)(ws + off); off += 1179648;
  unsigned short* We1l = (unsigned short*)(ws + off); off += 1179648;
  unsigned short* We2h = (unsigned short*)(ws + off); off += 1179648;
  unsigned short* We2l = (unsigned short*)(ws + off); off += 1179648;
  char* big = ws + off;
  size_t avail = (ws_size > off) ? ws_size - off : 0;

  // per-image bytes: h0hi/lo 2*100352 + h1hi/lo 2*25088 + u0t 32768 + a0t 32768 +
  // u1t 131072 + a1t 100352 + u2t 401408 + a2t 401408 = 1,350,656
  int NB = 512;
  while (NB > 1 && (size_t)NB * 1350656ull > avail) NB >>= 1;
  const int nch = 512 / NB;

  size_t o = 0;
  unsigned short* h0h = (unsigned short*)(big + o); o += (size_t)NB*100352;
  unsigned short* h0l = (unsigned short*)(big + o); o += (size_t)NB*100352;
  unsigned short* h1h = (unsigned short*)(big + o); o += (size_t)NB*25088;
  unsigned short* h1l = (unsigned short*)(big + o); o += (size_t)NB*25088;
  unsigned short* u0t = (unsigned short*)(big + o); o += (size_t)NB*32768;
  unsigned short* a0t = (unsigned short*)(big + o); o += (size_t)NB*32768;
  unsigned short* u1t = (unsigned short*)(big + o); o += (size_t)NB*131072;
  unsigned short* a1t = (unsigned short*)(big + o); o += (size_t)NB*100352;
  unsigned short* u2t = (unsigned short*)(big + o); o += (size_t)NB*401408;
  unsigned short* a2t = (unsigned short*)(big + o); o += (size_t)NB*401408;

  // ---- weight prep + codebook norms ----
  wprep2_kernel<<<CDIV(589824,256), 256, 0, stream>>>(Wd0, Wt0, Wt0l);
  wprep2_kernel<<<CDIV(589824,256), 256, 0, stream>>>(Wd1, Wt1, Wt1l);
  wprep2_kernel<<<CDIV(589824,256), 256, 0, stream>>>(Wd2, Wt2, Wt2l);
  wprep2_kernel<<<CDIV(589824,256), 256, 0, stream>>>(We1, We1h, We1l);
  wprep2_kernel<<<CDIV(589824,256), 256, 0, stream>>>(We2, We2h, We2l);
  enorm_kernel<<<16384, 256, 0, stream>>>(E, norms);

  // ---- encoder (bf16x3 split MFMA, chunked) ----
  for (int ch = 0; ch < nch; ++ch) {
    conv_e0_cl_kernel<<<NB, 256, 0, stream>>>(x + (size_t)ch*NB*784, We0, be0, h0h, h0l);
    // e1: 14x14 -> 7x7, stride 2, pad 1, relu, split in/out
    convmfma_kernel<2,7,7,8,2, 14,14,1,1,1,1><<<dim3(NB,4), 256, 0, stream>>>(
        h0h, h0l, (const vbf8*)We1h, (const vbf8*)We1l, be1, h1h, h1l, nullptr);
    // e2: 7x7 -> 4x4, stride 2, pad 1, no act, fp32 channel-major out (z_e)
    convmfma_kernel<2,4,4,4,4, 7,7,1,0,1,2><<<dim3(NB,1), 256, 0, stream>>>(
        h1h, h1l, (const vbf8*)We2h, (const vbf8*)We2l, be2, nullptr, nullptr,
        z_e + (size_t)ch*NB*4096);
  }
  // ---- VQ (fp32) ----
  perm_kernel<<<1, 512, 0, stream>>>(c, perm, offs, keys);
  vq_kernel<<<dim3(8,8,16), 256, 0, stream>>>(z_e, E, norms, perm, offs, keys);
  gather_t_kernel<<<512, 256, 0, stream>>>(keys, perm, E, zq, zqt);

  // ---- decoder (bf16 MFMA, channel-last, chunked) ----
  for (int ch = 0; ch < nch; ++ch) {
    const unsigned short* zt = zqt + (size_t)ch*NB*16*256;
    upsample_cl_kernel<4,4><<<CDIV(NB*2048,256), 256, 0, stream>>>(zt, u0t, NB);
    convmfma_kernel<1,8,8,8,8, 8,8,1,1,0,0><<<dim3(NB,1), 256, 0, stream>>>(
        u0t, nullptr, (const vbf8*)Wt0, nullptr, bd0, a0t, nullptr, nullptr);
    upsample_cl_kernel<8,8><<<CDIV(NB*8192,256), 256, 0, stream>>>(a0t, u1t, NB);
    convmfma_kernel<1,14,14,16,4, 16,16,0,1,0,0><<<dim3(NB,4), 256, 0, stream>>>(
        u1t, nullptr, (const vbf8*)Wt1, nullptr, bd1, a1t, nullptr, nullptr);
    upsample_cl_kernel<14,14><<<CDIV(NB*25088,256), 256, 0, stream>>>(a1t, u2t, NB);
    convmfma_kernel<1,28,28,28,4, 28,28,1,1,0,0><<<dim3(NB,7), 256, 0, stream>>>(
        u2t, nullptr, (const vbf8*)Wt2, nullptr, bd2, a2t, nullptr, nullptr);
    conv_out_t_kernel<<<dim3(NB,2), 256, 0, stream>>>(a2t, Wo, bo, out + (size_t)ch*NB*784);
  }
}

// Round 4
// 1919.546 us; speedup vs baseline: 15.4490x; 1.5579x over previous
//
#include <hip/hip_runtime.h>
#include <hip/hip_bf16.h>
#include <cstdint>
#include <cstddef>

#define CDIV(a,b) (((a)+(b)-1)/(b))

typedef __attribute__((ext_vector_type(8))) short vbf8;
typedef __attribute__((ext_vector_type(4))) float vf4;

__device__ inline unsigned short f2bf(float f) {
  unsigned u = __float_as_uint(f);
  unsigned r = (u + 0x7fffu + ((u >> 16) & 1u)) >> 16;
  return (unsigned short)r;
}
__device__ inline float bf2f(unsigned short h) { return __uint_as_float(((unsigned)h) << 16); }

// ============ encoder conv0: 1->256, 28->14, s2 p1, relu, ch-last hi/lo ========
__global__ __launch_bounds__(256) void conv_e0_cl_kernel(
    const float* __restrict__ x, const float* __restrict__ W,
    const float* __restrict__ b, unsigned short* __restrict__ hi,
    unsigned short* __restrict__ lo)
{
  __shared__ float s_img[784];
  const int n = blockIdx.x;
  const int co = threadIdx.x;
  for (int i = threadIdx.x; i < 784; i += 256) s_img[i] = x[(size_t)n*784 + i];
  float w[9];
#pragma unroll
  for (int t = 0; t < 9; ++t) w[t] = W[co*9 + t];
  const float bb = b[co];
  __syncthreads();
  for (int p = 0; p < 196; ++p) {
    int y = p / 14, xo = p % 14;
    float a = bb;
#pragma unroll
    for (int t = 0; t < 9; ++t) {
      int yi = 2*y + t/3 - 1, xi = 2*xo + t%3 - 1;
      if (yi >= 0 && yi < 28 && xi >= 0 && xi < 28) a = fmaf(w[t], s_img[yi*28 + xi], a);
    }
    a = fmaxf(a, 0.f);
    unsigned short h = f2bf(a);
    size_t oidx = ((size_t)n*196 + p)*256 + co;
    hi[oidx] = h;
    lo[oidx] = f2bf(a - bf2f(h));
  }
}

// ============ weight prep: W[co][ci][9] f32 -> [t][cig][co][8] bf16 hi/lo ======
__global__ __launch_bounds__(256) void wprep2_kernel(
    const float* __restrict__ W, unsigned short* __restrict__ Whi,
    unsigned short* __restrict__ Wlo)
{
  int idx = blockIdx.x*256 + threadIdx.x;
  if (idx >= 589824) return;
  int j   = idx & 7;
  int co  = (idx >> 3) & 255;
  int cig = (idx >> 11) & 31;
  int t   = idx >> 16;
  int ci  = cig*8 + j;
  float w = W[((size_t)co*256 + ci)*9 + t];
  unsigned short h = f2bf(w);
  Whi[idx] = h;
  Wlo[idx] = f2bf(w - bf2f(h));
}

// ============ unified bf16 MFMA 3x3 conv, channel-last =========================
template<int STRIDE, int HO, int WO, int WOP, int ROWS, int HI, int WI, int PAD,
         int ACT, int SPLIT, int OUTMODE>
__global__ __launch_bounds__(256, 2) void convmfma_kernel(
    const unsigned short* __restrict__ inT, const unsigned short* __restrict__ inTlo,
    const vbf8* __restrict__ Wt, const vbf8* __restrict__ Wtlo,
    const float* __restrict__ bias,
    unsigned short* __restrict__ outT, unsigned short* __restrict__ outTlo,
    float* __restrict__ outF)
{
  constexpr int NFM = ROWS*WOP/16;
  constexpr int RIN = (ROWS-1)*STRIDE + 3;
  constexpr int WS  = (WOP-1)*STRIDE + 3;
  constexpr int NG  = SPLIT ? 12 : 4;
  __shared__ vbf8 sA[RIN*WS*8];

  const int n  = blockIdx.x;
  const int y0 = blockIdx.y * ROWS;
  const int tid = threadIdx.x;
  const int lane = tid & 63;
  const int wv = tid >> 6;
  const int l15 = lane & 15;
  const int lq  = lane >> 4;
  const int cobase = wv * 64;

  int abase[NFM];
#pragma unroll
  for (int mf = 0; mf < NFM; ++mf) {
    int pos = mf*16 + l15;
    abase[mf] = (pos / WOP) * STRIDE * WS + (pos % WOP) * STRIDE;
  }

  vf4 acc[NFM][4];
#pragma unroll
  for (int mf = 0; mf < NFM; ++mf)
#pragma unroll
    for (int nf = 0; nf < 4; ++nf) acc[mf][nf] = (vf4){0.f, 0.f, 0.f, 0.f};

#pragma unroll 1
  for (int g = 0; g < NG; ++g) {
    const int cc = g & 3;
    const unsigned short* src = (SPLIT && g >= 8) ? inTlo : inT;
    const vbf8* wsrc = (SPLIT && g >= 4 && g < 8) ? Wtlo : Wt;
    for (int idx = tid; idx < RIN*WS*8; idx += 256) {
      int lin = idx >> 3, cig = idx & 7;
      int r = lin / WS, x = lin % WS;
      int yi = y0*STRIDE + r - PAD, xi = x - PAD;
      vbf8 v = {0,0,0,0,0,0,0,0};
      if (yi >= 0 && yi < HI && xi >= 0 && xi < WI)
        v = *(const vbf8*)(src + ((((size_t)n*HI + yi)*WI + xi)*256 + cc*64 + cig*8));
      sA[(lin*8 + cig) ^ (lin & 7)] = v;
    }
    __syncthreads();
#pragma unroll
    for (int t = 0; t < 9; ++t) {
      const int dy = t/3, dx = t%3;
#pragma unroll
      for (int kk = 0; kk < 2; ++kk) {
        vbf8 bfr[4];
        const int cig_g = cc*8 + kk*4 + lq;
#pragma unroll
        for (int nf = 0; nf < 4; ++nf)
          bfr[nf] = wsrc[((size_t)t*32 + cig_g)*256 + cobase + nf*16 + l15];
        vbf8 af[NFM];
        const int cigl = kk*4 + lq;
#pragma unroll
        for (int mf = 0; mf < NFM; ++mf) {
          int lin = abase[mf] + dy*WS + dx;
          af[mf] = sA[(lin*8 + cigl) ^ (lin & 7)];
        }
#pragma unroll
        for (int mf = 0; mf < NFM; ++mf)
#pragma unroll
          for (int nf = 0; nf < 4; ++nf)
            acc[mf][nf] = __builtin_amdgcn_mfma_f32_16x16x32_bf16(af[mf], bfr[nf], acc[mf][nf], 0, 0, 0);
      }
    }
    __syncthreads();
  }

  float bb[4];
#pragma unroll
  for (int nf = 0; nf < 4; ++nf) bb[nf] = bias[cobase + nf*16 + l15];
#pragma unroll
  for (int mf = 0; mf < NFM; ++mf) {
#pragma unroll
    for (int q = 0; q < 4; ++q) {
      int pos = mf*16 + lq*4 + q;
      int y = y0 + pos/WOP, x = pos % WOP;
      if (WOP > WO && x >= WO) continue;
      if (HO % ROWS != 0 && y >= HO) continue;
#pragma unroll
      for (int nf = 0; nf < 4; ++nf) {
        float v = acc[mf][nf][q] + bb[nf];
        if (ACT) v = fmaxf(v, 0.f);
        const int co = cobase + nf*16 + l15;
        if (OUTMODE == 2) {
          outF[((size_t)n*256 + co)*(HO*WO) + y*WO + x] = v;
        } else {
          size_t oidx = (((size_t)n*HO + y)*WO + x)*256 + co;
          unsigned short h = f2bf(v);
          outT[oidx] = h;
          if (OUTMODE == 1) outTlo[oidx] = f2bf(v - bf2f(h));
        }
      }
    }
  }
}

// ============ bilinear x2 upsample, channel-last bf16 ==========================
template<int H, int W>
__global__ __launch_bounds__(256) void upsample_cl_kernel(
    const unsigned short* __restrict__ in, unsigned short* __restrict__ out, int nimg)
{
  constexpr int Ho = 2*H, Wo = 2*W;
  int idx = blockIdx.x*256 + threadIdx.x;
  int total = nimg * Ho * Wo * 32;
  if (idx >= total) return;
  int cig = idx & 31; int rest = idx >> 5;
  int xo = rest % Wo; rest /= Wo;
  int yo = rest % Ho; int n = rest / Ho;
  float ys = (float)(yo*(H-1)) / (float)(Ho-1);
  float xs = (float)(xo*(W-1)) / (float)(Wo-1);
  int ya = (int)ys; int yb = (ya+1 < H) ? ya+1 : H-1;
  int xa = (int)xs; int xb = (xa+1 < W) ? xa+1 : W-1;
  float wy = ys - (float)ya, wx = xs - (float)xa;
  const unsigned short* base = in + (size_t)n*H*W*256 + cig*8;
  vbf8 vaa = *(const vbf8*)(base + ((size_t)ya*W + xa)*256);
  vbf8 vab = *(const vbf8*)(base + ((size_t)ya*W + xb)*256);
  vbf8 vba = *(const vbf8*)(base + ((size_t)yb*W + xa)*256);
  vbf8 vbb = *(const vbf8*)(base + ((size_t)yb*W + xb)*256);
  vbf8 o;
#pragma unroll
  for (int j = 0; j < 8; ++j) {
    float r0 = bf2f((unsigned short)vaa[j])*(1.f-wy) + bf2f((unsigned short)vba[j])*wy;
    float r1 = bf2f((unsigned short)vab[j])*(1.f-wy) + bf2f((unsigned short)vbb[j])*wy;
    o[j] = (short)f2bf(r0*(1.f-wx) + r1*wx);
  }
  *(vbf8*)(out + (((size_t)n*Ho + yo)*Wo + xo)*256 + cig*8) = o;
}

// ============ output conv: 256->1, 3x3 pad1, sigmoid (channel-last) ============
__global__ __launch_bounds__(256) void conv_out_t_kernel(
    const unsigned short* __restrict__ a2t, const float* __restrict__ Wo,
    const float* __restrict__ bo, float* __restrict__ out)
{
  const int n = blockIdx.x;
  const int y0 = blockIdx.y * 14;
  const int tid = threadIdx.x;
  __shared__ vbf8 s_in[16*30*8];
  __shared__ float s_w[9*64];
  float acc[2] = {0.f, 0.f};
  for (int cc = 0; cc < 4; ++cc) {
    for (int idx = tid; idx < 16*30*8; idx += 256) {
      int lin = idx >> 3, cig = idx & 7;
      int r = lin / 30, xx = lin % 30;
      int yi = y0 + r - 1, xi = xx - 1;
      vbf8 v = {0,0,0,0,0,0,0,0};
      if (yi >= 0 && yi < 28 && xi >= 0 && xi < 28)
        v = *(const vbf8*)(a2t + (((size_t)n*28 + yi)*28 + xi)*256 + cc*64 + cig*8);
      s_in[(lin*8 + cig) ^ (lin & 7)] = v;
    }
    for (int idx = tid; idx < 576; idx += 256) {
      int t = idx / 64, cil = idx % 64;
      s_w[t*64 + cil] = Wo[((size_t)cc*64 + cil)*9 + t];
    }
    __syncthreads();
#pragma unroll
    for (int q = 0; q < 2; ++q) {
      int p = tid + q*256;
      if (p < 392) {
        int y = p / 28, x = p % 28;
        float a = acc[q];
#pragma unroll
        for (int t = 0; t < 9; ++t) {
          int lin = (y + t/3)*30 + (x + t%3);
#pragma unroll
          for (int cig = 0; cig < 8; ++cig) {
            vbf8 v = s_in[(lin*8 + cig) ^ (lin & 7)];
#pragma unroll
            for (int j = 0; j < 8; ++j)
              a = fmaf(bf2f((unsigned short)v[j]), s_w[t*64 + cig*8 + j], a);
          }
        }
        acc[q] = a;
      }
    }
    __syncthreads();
  }
  const float bb = bo[0];
  for (int q = 0; q < 2; ++q) {
    int p = tid + q*256;
    if (p < 392) {
      int y = y0 + p/28, x = p%28;
      out[(size_t)n*784 + y*28 + x] = 1.f/(1.f + expf(-(acc[q] + bb)));
    }
  }
}

// ============ VQ: codebook norms ===============================================
__global__ __launch_bounds__(256) void enorm_kernel(
    const float* __restrict__ E, float* __restrict__ norms)
{
  const int k = blockIdx.x;
  const float4* row = (const float4*)(E + (size_t)k*4096);
  float s = 0.f;
  for (int i = threadIdx.x; i < 1024; i += 256) {
    float4 v = row[i];
    s += v.x*v.x + v.y*v.y + v.z*v.z + v.w*v.w;
  }
  __shared__ float red[256];
  red[threadIdx.x] = s; __syncthreads();
  for (int off = 128; off > 0; off >>= 1) {
    if (threadIdx.x < off) red[threadIdx.x] += red[threadIdx.x + off];
    __syncthreads();
  }
  if (threadIdx.x == 0) norms[k] = red[0];
}

// ============ VQ: E fp32 [16384][4096] -> Et bf16 [512 kg][16384][8] ===========
__global__ __launch_bounds__(256) void etrans_kernel(
    const float* __restrict__ E, unsigned short* __restrict__ Et)
{
  const int cb = blockIdx.x;   // 0..255 (64 codes)
  const int kb = blockIdx.y;   // 0..63  (64 k)
  const int t = threadIdx.x;
  const int cl = t >> 2;
  const int seg = t & 3;
  const int code = cb*64 + cl;
  const int k0 = kb*64 + seg*16;
  const float4* src = (const float4*)(E + (size_t)code*4096 + k0);
  float4 v0 = src[0], v1 = src[1], v2 = src[2], v3 = src[3];
  vbf8 a, b;
  a[0]=(short)f2bf(v0.x); a[1]=(short)f2bf(v0.y); a[2]=(short)f2bf(v0.z); a[3]=(short)f2bf(v0.w);
  a[4]=(short)f2bf(v1.x); a[5]=(short)f2bf(v1.y); a[6]=(short)f2bf(v1.z); a[7]=(short)f2bf(v1.w);
  b[0]=(short)f2bf(v2.x); b[1]=(short)f2bf(v2.y); b[2]=(short)f2bf(v2.z); b[3]=(short)f2bf(v2.w);
  b[4]=(short)f2bf(v3.x); b[5]=(short)f2bf(v3.y); b[6]=(short)f2bf(v3.z); b[7]=(short)f2bf(v3.w);
  vbf8* dst = (vbf8*)Et;
  dst[(size_t)(k0 >> 3)*16384 + code]     = a;
  dst[((size_t)(k0 >> 3) + 1)*16384 + code] = b;
}

// ============ VQ: stable counting-sort permutation by class ====================
__global__ __launch_bounds__(512) void perm_kernel(
    const int* __restrict__ c, int* __restrict__ perm, int* __restrict__ off)
{
  __shared__ int sc[512];
  __shared__ int cnt[8];
  __shared__ int base[9];
  const int i = threadIdx.x;
  sc[i] = c[i];
  if (i < 8) cnt[i] = 0;
  __syncthreads();
  atomicAdd(&cnt[sc[i]], 1);
  __syncthreads();
  if (i == 0) { int a = 0; for (int j = 0; j < 8; ++j) { base[j] = a; a += cnt[j]; } base[8] = a; }
  __syncthreads();
  const int ci = sc[i];
  int rank = 0;
  for (int j = 0; j < i; ++j) rank += (sc[j] == ci) ? 1 : 0;
  perm[base[ci] + rank] = i;
  if (i < 9) off[i] = base[i];
}

// ============ VQ: coarse bf16 MFMA distance GEMM ===============================
// A: 64 samples (class bucket) x K=4096 (LDS, XOR-swizzled), B: Et direct.
// dco[s][j] = norms[cls*2048+j] - 2*<z_s, e_j>   (coarse, bf16 inputs)
__global__ __launch_bounds__(256) void vq_coarse_kernel(
    const float* __restrict__ zE, const vbf8* __restrict__ Etv,
    const float* __restrict__ norms, const int* __restrict__ perm,
    const int* __restrict__ offs, float* __restrict__ dco)
{
  const int cls = blockIdx.x;   // 8
  const int mb  = blockIdx.y;   // 8
  const int kb  = blockIdx.z;   // 8 (256 codes each)
  const int s0 = offs[cls];
  const int total = offs[cls+1] - s0;
  int nrows = total - mb*64;
  if (nrows <= 0) return;
  if (nrows > 64) nrows = 64;

  __shared__ vbf8 sA[64*8];
  __shared__ int srow_s[64];
  const int tid = threadIdx.x;
  if (tid < 64) srow_s[tid] = (tid < nrows) ? perm[s0 + mb*64 + tid] : -1;
  __syncthreads();

  const int lane = tid & 63;
  const int wv = tid >> 6;
  const int l15 = lane & 15;
  const int lq  = lane >> 4;

  const int myrow = tid >> 2;
  const int seg = tid & 3;
  const int srow_mine = srow_s[myrow];
  const float* zbase = (srow_mine >= 0) ? (zE + (size_t)srow_mine*4096 + seg*16) : nullptr;

  const int cbase = cls*2048 + kb*256 + wv*64;   // global code base for this wave

  vf4 acc[4][4];
#pragma unroll
  for (int mf = 0; mf < 4; ++mf)
#pragma unroll
    for (int nf = 0; nf < 4; ++nf) acc[mf][nf] = (vf4){0.f, 0.f, 0.f, 0.f};

#pragma unroll 1
  for (int k0 = 0; k0 < 4096; k0 += 64) {
    {
      float4 v0, v1, v2, v3;
      if (zbase) {
        const float4* p = (const float4*)(zbase + k0);
        v0 = p[0]; v1 = p[1]; v2 = p[2]; v3 = p[3];
      } else {
        v0 = v1 = v2 = v3 = (float4){0.f, 0.f, 0.f, 0.f};
      }
      vbf8 a, b;
      a[0]=(short)f2bf(v0.x); a[1]=(short)f2bf(v0.y); a[2]=(short)f2bf(v0.z); a[3]=(short)f2bf(v0.w);
      a[4]=(short)f2bf(v1.x); a[5]=(short)f2bf(v1.y); a[6]=(short)f2bf(v1.z); a[7]=(short)f2bf(v1.w);
      b[0]=(short)f2bf(v2.x); b[1]=(short)f2bf(v2.y); b[2]=(short)f2bf(v2.z); b[3]=(short)f2bf(v2.w);
      b[4]=(short)f2bf(v3.x); b[5]=(short)f2bf(v3.y); b[6]=(short)f2bf(v3.z); b[7]=(short)f2bf(v3.w);
      int c0 = seg*2;
      sA[myrow*8 + (c0 ^ (myrow & 7))]       = a;
      sA[myrow*8 + ((c0 + 1) ^ (myrow & 7))] = b;
    }
    __syncthreads();
#pragma unroll
    for (int kb32 = 0; kb32 < 2; ++kb32) {
      vbf8 af[4], bf[4];
#pragma unroll
      for (int mf = 0; mf < 4; ++mf) {
        int row = mf*16 + l15;
        af[mf] = sA[row*8 + ((kb32*4 + lq) ^ (row & 7))];
      }
      const size_t kg = (size_t)((k0 >> 3) + kb32*4 + lq);
#pragma unroll
      for (int nf = 0; nf < 4; ++nf)
        bf[nf] = Etv[kg*16384 + cbase + nf*16 + l15];
#pragma unroll
      for (int mf = 0; mf < 4; ++mf)
#pragma unroll
        for (int nf = 0; nf < 4; ++nf)
          acc[mf][nf] = __builtin_amdgcn_mfma_f32_16x16x32_bf16(af[mf], bf[nf], acc[mf][nf], 0, 0, 0);
    }
    __syncthreads();
  }

  float nrm[4];
#pragma unroll
  for (int nf = 0; nf < 4; ++nf) nrm[nf] = norms[cbase + nf*16 + l15];
#pragma unroll
  for (int mf = 0; mf < 4; ++mf) {
#pragma unroll
    for (int q = 0; q < 4; ++q) {
      int slot = mf*16 + lq*4 + q;
      if (slot < nrows) {
        int s = srow_s[slot];
        float* drow = dco + (size_t)s*2048 + (kb*256 + wv*64);
#pragma unroll
        for (int nf = 0; nf < 4; ++nf)
          drow[nf*16 + l15] = nrm[nf] - 2.f*acc[mf][nf][q];
      }
    }
  }
}

// ============ VQ: candidate selection + exact fp64 rescore =====================
__global__ __launch_bounds__(256) void vq_select_kernel(
    const float* __restrict__ dco, const int* __restrict__ c,
    const float* __restrict__ zE, const float* __restrict__ E,
    int* __restrict__ codes)
{
  const int s = blockIdx.x;
  const int cls = c[s];
  const int tid = threadIdx.x;
  const float* drow = dco + (size_t)s*2048;

  float mn = 3.4e38f, mx = -3.4e38f;
  for (int j = tid; j < 2048; j += 256) {
    float d = drow[j];
    mn = fminf(mn, d); mx = fmaxf(mx, d);
  }
  __shared__ float smn[256], smx[256];
  smn[tid] = mn; smx[tid] = mx;
  __syncthreads();
  for (int o = 128; o > 0; o >>= 1) {
    if (tid < o) { smn[tid] = fminf(smn[tid], smn[tid+o]); smx[tid] = fmaxf(smx[tid], smx[tid+o]); }
    __syncthreads();
  }
  const float dmin = smn[0], dmax = smx[0];
  const float margin = 0.06f*(dmax - dmin) + 1e-6f*fabsf(dmin) + 1e-20f;

  __shared__ int cand[64];
  __shared__ int cnt_s;
  if (tid == 0) cnt_s = 0;
  __syncthreads();
  for (int j = tid; j < 2048; j += 256) {
    if (drow[j] <= dmin + margin) {
      int p = atomicAdd(&cnt_s, 1);
      if (p < 64) cand[p] = j;
    }
  }
  __syncthreads();
  const int cnt = (cnt_s < 64) ? cnt_s : 64;

  __shared__ double red[256];
  __shared__ double bestd_s;
  __shared__ int bestc_s;
  if (tid == 0) { bestd_s = 1.0e300; bestc_s = 0x7fffffff; }
  __syncthreads();
  const float* zrow = zE + (size_t)s*4096;
  for (int t = 0; t < cnt; ++t) {
    const int gcode = cls*2048 + cand[t];
    const float* erow = E + (size_t)gcode*4096;
    double p = 0.0;
    for (int e2 = tid; e2 < 4096; e2 += 256) {
      double ev = (double)erow[e2];
      double zv = (double)zrow[e2];
      p += ev*ev - 2.0*zv*ev;
    }
    red[tid] = p;
    __syncthreads();
    for (int o = 128; o > 0; o >>= 1) {
      if (tid < o) red[tid] += red[tid+o];
      __syncthreads();
    }
    if (tid == 0) {
      double d = red[0];
      if (d < bestd_s || (d == bestd_s && gcode < bestc_s)) { bestd_s = d; bestc_s = gcode; }
    }
    __syncthreads();
  }
  if (tid == 0) codes[s] = bestc_s;
}

// gather: zq fp32 (output, channel-major) + zqt bf16 (channel-last for decoder)
__global__ __launch_bounds__(256) void gather_t_kernel(
    const int* __restrict__ codes, const int* __restrict__ perm,
    const float* __restrict__ E, float* __restrict__ zq, unsigned short* __restrict__ zqt)
{
  const int i = blockIdx.x;
  const int s = perm[i];
  const int code = codes[s];
  const float4* src = (const float4*)(E + (size_t)code*4096);
  float4* dst = (float4*)(zq + (size_t)i*4096);
  for (int t = threadIdx.x; t < 1024; t += 256) {
    float4 v = src[t];
    dst[t] = v;
    int e0 = t*4;
    int ci = e0 >> 4, sp = e0 & 15;
    unsigned short* zp = zqt + ((size_t)i*16 + sp)*256 + ci;
    zp[0]   = f2bf(v.x);
    zp[256] = f2bf(v.y);
    zp[512] = f2bf(v.z);
    zp[768] = f2bf(v.w);
  }
}

// ============ driver ===========================================================
extern "C" void kernel_launch(void* const* d_in, const int* in_sizes, int n_in,
                              void* d_out, int out_size, void* d_ws, size_t ws_size,
                              hipStream_t stream) {
  const float* x   = (const float*)d_in[0];
  const float* We0 = (const float*)d_in[1];
  const float* be0 = (const float*)d_in[2];
  const float* We1 = (const float*)d_in[3];
  const float* be1 = (const float*)d_in[4];
  const float* We2 = (const float*)d_in[5];
  const float* be2 = (const float*)d_in[6];
  const float* E   = (const float*)d_in[7];
  const float* Wd0 = (const float*)d_in[8];
  const float* bd0 = (const float*)d_in[9];
  const float* Wd1 = (const float*)d_in[10];
  const float* bd1 = (const float*)d_in[11];
  const float* Wd2 = (const float*)d_in[12];
  const float* bd2 = (const float*)d_in[13];
  const float* Wo  = (const float*)d_in[14];
  const float* bo  = (const float*)d_in[15];
  const int*   c   = (const int*)d_in[16];

  float* out = (float*)d_out;
  float* z_e = out + (size_t)512*784;
  float* zq  = z_e + (size_t)512*4096;

  char* ws = (char*)d_ws;
  size_t off = 0;
  float* norms = (float*)(ws + off); off += 65536;
  int* codes = (int*)(ws + off); off += 2048;
  int* perm = (int*)(ws + off); off += 2048;
  int* offs = (int*)(ws + off); off += 256;
  float* dco = (float*)(ws + off); off += (size_t)512*2048*4;
  unsigned short* zqt = (unsigned short*)(ws + off); off += (size_t)512*16*256*2;
  unsigned short* Et = (unsigned short*)(ws + off); off += (size_t)512*16384*8*2;
  unsigned short* Wt0  = (unsigned short*)(ws + off); off += 1179648;
  unsigned short* Wt0l = (unsigned short*)(ws + off); off += 1179648;
  unsigned short* Wt1  = (unsigned short*)(ws + off); off += 1179648;
  unsigned short* Wt1l = (unsigned short*)(ws + off); off += 1179648;
  unsigned short* Wt2  = (unsigned short*)(ws + off); off += 1179648;
  unsigned short* Wt2l = (unsigned short*)(ws + off); off += 1179648;
  unsigned short* We1h = (unsigned short*)(ws + off); off += 1179648;
  unsigned short* We1l = (unsigned short*)(ws + off); off += 1179648;
  unsigned short* We2h = (unsigned short*)(ws + off); off += 1179648;
  unsigned short* We2l = (unsigned short*)(ws + off); off += 1179648;
  char* big = ws + off;
  size_t avail = (ws_size > off) ? ws_size - off : 0;

  int NB = 512;
  while (NB > 1 && (size_t)NB * 1350656ull > avail) NB >>= 1;
  const int nch = 512 / NB;

  size_t o = 0;
  unsigned short* h0h = (unsigned short*)(big + o); o += (size_t)NB*100352;
  unsigned short* h0l = (unsigned short*)(big + o); o += (size_t)NB*100352;
  unsigned short* h1h = (unsigned short*)(big + o); o += (size_t)NB*25088;
  unsigned short* h1l = (unsigned short*)(big + o); o += (size_t)NB*25088;
  unsigned short* u0t = (unsigned short*)(big + o); o += (size_t)NB*32768;
  unsigned short* a0t = (unsigned short*)(big + o); o += (size_t)NB*32768;
  unsigned short* u1t = (unsigned short*)(big + o); o += (size_t)NB*131072;
  unsigned short* a1t = (unsigned short*)(big + o); o += (size_t)NB*100352;
  unsigned short* u2t = (unsigned short*)(big + o); o += (size_t)NB*401408;
  unsigned short* a2t = (unsigned short*)(big + o); o += (size_t)NB*401408;

  // ---- weight prep + codebook prep ----
  wprep2_kernel<<<CDIV(589824,256), 256, 0, stream>>>(Wd0, Wt0, Wt0l);
  wprep2_kernel<<<CDIV(589824,256), 256, 0, stream>>>(Wd1, Wt1, Wt1l);
  wprep2_kernel<<<CDIV(589824,256), 256, 0, stream>>>(Wd2, Wt2, Wt2l);
  wprep2_kernel<<<CDIV(589824,256), 256, 0, stream>>>(We1, We1h, We1l);
  wprep2_kernel<<<CDIV(589824,256), 256, 0, stream>>>(We2, We2h, We2l);
  enorm_kernel<<<16384, 256, 0, stream>>>(E, norms);
  etrans_kernel<<<dim3(256,64), 256, 0, stream>>>(E, Et);

  // ---- encoder (bf16x3 split MFMA, chunked) ----
  for (int ch = 0; ch < nch; ++ch) {
    conv_e0_cl_kernel<<<NB, 256, 0, stream>>>(x + (size_t)ch*NB*784, We0, be0, h0h, h0l);
    convmfma_kernel<2,7,7,8,2, 14,14,1,1,1,1><<<dim3(NB,4), 256, 0, stream>>>(
        h0h, h0l, (const vbf8*)We1h, (const vbf8*)We1l, be1, h1h, h1l, nullptr);
    convmfma_kernel<2,4,4,4,4, 7,7,1,0,1,2><<<dim3(NB,1), 256, 0, stream>>>(
        h1h, h1l, (const vbf8*)We2h, (const vbf8*)We2l, be2, nullptr, nullptr,
        z_e + (size_t)ch*NB*4096);
  }
  // ---- VQ: coarse MFMA + exact rescore ----
  perm_kernel<<<1, 512, 0, stream>>>(c, perm, offs);
  vq_coarse_kernel<<<dim3(8,8,8), 256, 0, stream>>>(
      z_e, (const vbf8*)Et, norms, perm, offs, dco);
  vq_select_kernel<<<512, 256, 0, stream>>>(dco, c, z_e, E, codes);
  gather_t_kernel<<<512, 256, 0, stream>>>(codes, perm, E, zq, zqt);

  // ---- decoder (bf16 MFMA, channel-last, chunked) ----
  for (int ch = 0; ch < nch; ++ch) {
    const unsigned short* zt = zqt + (size_t)ch*NB*16*256;
    upsample_cl_kernel<4,4><<<CDIV(NB*2048,256), 256, 0, stream>>>(zt, u0t, NB);
    convmfma_kernel<1,8,8,8,8, 8,8,1,1,0,0><<<dim3(NB,1), 256, 0, stream>>>(
        u0t, nullptr, (const vbf8*)Wt0, nullptr, bd0, a0t, nullptr, nullptr);
    upsample_cl_kernel<8,8><<<CDIV(NB*8192,256), 256, 0, stream>>>(a0t, u1t, NB);
    convmfma_kernel<1,14,14,16,4, 16,16,0,1,0,0><<<dim3(NB,4), 256, 0, stream>>>(
        u1t, nullptr, (const vbf8*)Wt1, nullptr, bd1, a1t, nullptr, nullptr);
    upsample_cl_kernel<14,14><<<CDIV(NB*25088,256), 256, 0, stream>>>(a1t, u2t, NB);
    convmfma_kernel<1,28,28,28,4, 28,28,1,1,0,0><<<dim3(NB,7), 256, 0, stream>>>(
        u2t, nullptr, (const vbf8*)Wt2, nullptr, bd2, a2t, nullptr, nullptr);
    conv_out_t_kernel<<<dim3(NB,2), 256, 0, stream>>>(a2t, Wo, bo, out + (size_t)ch*NB*784);
  }
}